// Round 5
// baseline (436.572 us; speedup 1.0000x reference)
//
#include <hip/hip_runtime.h>
#include <hip/hip_bf16.h>
#include <stdint.h>

// ---------------------------------------------------------------------------
// TransformerDecoderBlock on MI355X (gfx950).  B=2, T=2048, C=1024, H=16, hd=64.
// R8:  64^2 tiles for N=1024 GEMMs, 16 waves/CU, drain-0 dbuf.   [best: 325.7us]
// R9-R12 all FAILED: ring-buf (codegen), 128x64 / 128^2 (occupancy),
//      BK=32 chunk-rot swizzle (4M bank conflicts) + pointless split-K.
// R13: flatmm for Wo/FF2 -- A fragments loaded DIRECT from global (row-major,
//      frag = 8 contiguous K-elems -> one dwordx4/lane; 16 rows x 64B
//      segments, L1/L2-served, A panel reused by 16 N-blocks). B-only LDS
//      (16KB dbuf, proven 8-chunk swizzle) -> LDS ratio 1.0 -> 0.5 while
//      KEEPING 1024 blocks. Unroll-2 loop, A prefetch in named reg sets.
//      qkv/FF1 back on proven 128^2 gemm_k.
// ---------------------------------------------------------------------------

typedef __attribute__((ext_vector_type(8))) short bf16x8;   // 8 bf16 in 4 VGPRs
typedef __attribute__((ext_vector_type(4))) float f32x4;

#define MFMA16(a, b, c) __builtin_amdgcn_mfma_f32_16x16x32_bf16((a), (b), (c), 0, 0, 0)

__device__ __forceinline__ void gload16(const void* g, void* l) {
    __builtin_amdgcn_global_load_lds(
        (const __attribute__((address_space(1))) char*)g,
        (__attribute__((address_space(3))) char*)l, 16, 0, 0);
}

// XCD-aware remap: contiguous chunk of work per XCD (XCD = dispatch id % 8).
__device__ __forceinline__ int xcd_swizzle(int flat, int nblk) {
    if ((nblk & 7) == 0) {
        const int per = nblk >> 3;
        flat = (flat & 7) * per + (flat >> 3);
    }
    return flat;
}

// ---------------- merged transpose + fp32->bf16 for all 4 weights -----------
__global__ __launch_bounds__(256) void tconv_all(
    const float* __restrict__ w0, __hip_bfloat16* __restrict__ o0,   // 1024x3072
    const float* __restrict__ w1, __hip_bfloat16* __restrict__ o1,   // 1024x1024
    const float* __restrict__ w2, __hip_bfloat16* __restrict__ o2,   // 1024x4096
    const float* __restrict__ w3, __hip_bfloat16* __restrict__ o3) { // 4096x1024
    __shared__ float tile[32][33];
    const int f = blockIdx.x;
    const float* in; __hip_bfloat16* out; int K, N, nx, t;
    if (f < 3072)      { in = w0; out = o0; K = 1024; N = 3072; nx = 96;  t = f; }
    else if (f < 4096) { in = w1; out = o1; K = 1024; N = 1024; nx = 32;  t = f - 3072; }
    else if (f < 8192) { in = w2; out = o2; K = 1024; N = 4096; nx = 128; t = f - 4096; }
    else               { in = w3; out = o3; K = 4096; N = 1024; nx = 32;  t = f - 8192; }
    const int n0 = (t % nx) * 32, k0 = (t / nx) * 32;
    const int tx = threadIdx.x, ty = threadIdx.y;   // block (32, 8)
    for (int i = ty; i < 32; i += 8)
        tile[i][tx] = in[(size_t)(k0 + i) * N + n0 + tx];
    __syncthreads();
    for (int i = ty; i < 32; i += 8)
        out[(size_t)(n0 + i) * K + k0 + tx] = __float2bfloat16(tile[tx][i]);
}

// --------------------------------- layernorm -------------------------------
__global__ __launch_bounds__(256) void ln_k(const float* __restrict__ x,
                                            const float* __restrict__ g,
                                            const float* __restrict__ beta,
                                            __hip_bfloat16* __restrict__ out) {
    const int row = blockIdx.x;
    const int tid = threadIdx.x;
    float4 v = ((const float4*)(x + (size_t)row * 1024))[tid];
    float s  = v.x + v.y + v.z + v.w;
    float s2 = v.x * v.x + v.y * v.y + v.z * v.z + v.w * v.w;
    for (int off = 1; off < 64; off <<= 1) {
        s  += __shfl_xor(s,  off, 64);
        s2 += __shfl_xor(s2, off, 64);
    }
    __shared__ float ss[4], ss2[4];
    const int w = tid >> 6, lane = tid & 63;
    if (lane == 0) { ss[w] = s; ss2[w] = s2; }
    __syncthreads();
    s  = ss[0] + ss[1] + ss[2] + ss[3];
    s2 = ss2[0] + ss2[1] + ss2[2] + ss2[3];
    const float mu  = s * (1.0f / 1024.0f);
    const float var = s2 * (1.0f / 1024.0f) - mu * mu;
    const float rs  = rsqrtf(var + 1e-5f);
    float4 gv = ((const float4*)g)[tid];
    float4 bv = ((const float4*)beta)[tid];
    __hip_bfloat16* o = out + (size_t)row * 1024 + tid * 4;
    o[0] = __float2bfloat16((v.x - mu) * rs * gv.x + bv.x);
    o[1] = __float2bfloat16((v.y - mu) * rs * gv.y + bv.y);
    o[2] = __float2bfloat16((v.z - mu) * rs * gv.z + bv.z);
    o[3] = __float2bfloat16((v.w - mu) * rs * gv.w + bv.w);
}

// ------------------- GEMM, BM=128 BN=128 BK=64, dbuf 1-barrier ---------------
template <int BIAS, int RELU, int RESID, int OUTBF>
__global__ __launch_bounds__(256, 2) void gemm_k(const __hip_bfloat16* __restrict__ A,
                                                 const __hip_bfloat16* __restrict__ Bt,
                                                 const float* __restrict__ bias,
                                                 const float* __restrict__ resid,
                                                 void* __restrict__ out,
                                                 int M, int N, int K) {
    __align__(16) __shared__ __hip_bfloat16 As[2][128 * 64];
    __align__(16) __shared__ __hip_bfloat16 Bs[2][128 * 64];

    const int tid  = threadIdx.x;
    const int lane = tid & 63, w = tid >> 6;
    const int wm = w >> 1, wn = w & 1;
    const int nbx = gridDim.x;
    const int flat = xcd_swizzle(blockIdx.y * nbx + blockIdx.x, nbx * gridDim.y);
    const int m0 = (flat / nbx) * 128, n0 = (flat % nbx) * 128;
    const int l16 = lane & 15, quad = lane >> 4;

    const int srw = lane >> 3;                 // 0..7
    const int scn = ((lane & 7) - srw) & 7;    // source chunk (swizzled)

    const __hip_bfloat16* ga[4];
    const __hip_bfloat16* gb[4];
#pragma unroll
    for (int i = 0; i < 4; i++) {
        const int row = i * 32 + w * 8 + srw;
        ga[i] = A  + (size_t)(m0 + row) * K + scn * 8;
        gb[i] = Bt + (size_t)(n0 + row) * K + scn * 8;
    }

    int offA[2][4], offB[2][4];
#pragma unroll
    for (int s = 0; s < 2; s++)
#pragma unroll
        for (int t = 0; t < 4; t++) {
            const int rA = wm * 64 + t * 16 + l16;
            offA[s][t] = (rA * 8 + ((s * 4 + quad + (rA & 7)) & 7)) * 16;
            const int rB = wn * 64 + t * 16 + l16;
            offB[s][t] = (rB * 8 + ((s * 4 + quad + (rB & 7)) & 7)) * 16;
        }

    f32x4 acc[4][4] = {};

#pragma unroll
    for (int i = 0; i < 4; i++) {
        gload16(ga[i], As[0] + (i * 256 + w * 64) * 8);
        gload16(gb[i], Bs[0] + (i * 256 + w * 64) * 8);
        ga[i] += 64; gb[i] += 64;
    }

    const int niter = K >> 6;
    for (int it = 0; it < niter; it++) {
        const int buf = it & 1;
        __syncthreads();   // drains prefetch into buf (issued prev iter)
        if (it + 1 < niter) {
#pragma unroll
            for (int i = 0; i < 4; i++) {
                gload16(ga[i], As[buf ^ 1] + (i * 256 + w * 64) * 8);
                gload16(gb[i], Bs[buf ^ 1] + (i * 256 + w * 64) * 8);
                ga[i] += 64; gb[i] += 64;
            }
        }

#pragma unroll
        for (int s = 0; s < 2; s++) {
            bf16x8 af[4], bfr[4];
#pragma unroll
            for (int t = 0; t < 4; t++) {
                af[t]  = *(const bf16x8*)((const char*)As[buf] + offA[s][t]);
                bfr[t] = *(const bf16x8*)((const char*)Bs[buf] + offB[s][t]);
            }
#pragma unroll
            for (int mt = 0; mt < 4; mt++)
#pragma unroll
                for (int nt = 0; nt < 4; nt++)
                    acc[mt][nt] = MFMA16(af[mt], bfr[nt], acc[mt][nt]);
        }
    }

#pragma unroll
    for (int mt = 0; mt < 4; mt++)
#pragma unroll
        for (int nt = 0; nt < 4; nt++) {
            const int row = m0 + wm * 64 + mt * 16 + quad * 4;
            const int col = n0 + wn * 64 + nt * 16 + l16;
            const float bv = BIAS ? bias[col] : 0.0f;
#pragma unroll
            for (int r = 0; r < 4; r++) {
                float v = acc[mt][nt][r] + bv;
                if (RELU) v = v > 0.0f ? v : 0.0f;
                const size_t idx = (size_t)(row + r) * N + col;
                if (RESID) v += resid[idx];
                if (OUTBF) ((__hip_bfloat16*)out)[idx] = __float2bfloat16(v);
                else       ((float*)out)[idx] = v;
            }
        }
}

// ------------- flatmm GEMM: BM=64 BN=64 BK=64, A direct from global ---------
// B staged in LDS (16KB dbuf, proven 8-chunk swizzle, 0 conflicts); A frags
// loaded straight from global: lane (quad,l16) reads 16B at row(l16)*K +
// quad*8 elems -> 16 rows x 64B contiguous segments per instr; A panel is
// L1/L2-resident (reused by all N/64 blocks, XCD-swizzled together).
// LDS reads/MFMA = 0.5 at 64^2-tile occupancy (1024 blocks for N=1024).
// Unroll-2 K-loop; A prefetched one iter ahead into NAMED reg sets (afa/afb,
// all indices compile-time); the inter-half barrier drain covers A latency.
template <int BIAS, int RELU, int RESID, int OUTBF>
__global__ __launch_bounds__(256, 4) void gemm_flat_k(const __hip_bfloat16* __restrict__ A,
                                                      const __hip_bfloat16* __restrict__ Bt,
                                                      const float* __restrict__ bias,
                                                      const float* __restrict__ resid,
                                                      void* __restrict__ out,
                                                      int M, int N, int K) {
    __align__(16) __shared__ __hip_bfloat16 Bs[2][64 * 64];

    const int tid  = threadIdx.x;
    const int lane = tid & 63, w = tid >> 6;
    const int wm = w >> 1, wn = w & 1;             // 2x2 wave grid of 32x32
    const int nbx = gridDim.x;
    const int flat = xcd_swizzle(blockIdx.y * nbx + blockIdx.x, nbx * gridDim.y);
    const int m0 = (flat / nbx) * 64, n0 = (flat % nbx) * 64;
    const int l16 = lane & 15, quad = lane >> 4;

    const int srw = lane >> 3;
    const int scn = ((lane & 7) - srw) & 7;

    const __hip_bfloat16* gb[2];
#pragma unroll
    for (int i = 0; i < 2; i++) {
        const int row = i * 32 + w * 8 + srw;
        gb[i] = Bt + (size_t)(n0 + row) * K + scn * 8;
    }

    int offB[2][2];
#pragma unroll
    for (int s = 0; s < 2; s++)
#pragma unroll
        for (int t = 0; t < 2; t++) {
            const int rB = wn * 32 + t * 16 + l16;
            offB[s][t] = (rB * 8 + ((s * 4 + quad + (rB & 7)) & 7)) * 16;
        }

    // A fragment base: row (m0 + wm*32 + l16), k-offset quad*8.
    const __hip_bfloat16* pA = A + (size_t)(m0 + wm * 32 + l16) * K + quad * 8;

    f32x4 acc[2][2] = {};
    bf16x8 afa[2][2], afb[2][2];

    // prologue: stage B tile 0, load A frags for it=0
#pragma unroll
    for (int i = 0; i < 2; i++) {
        gload16(gb[i], Bs[0] + (i * 256 + w * 64) * 8);
        gb[i] += 64;
    }
#pragma unroll
    for (int s = 0; s < 2; s++)
#pragma unroll
        for (int t = 0; t < 2; t++)
            afa[s][t] = *(const bf16x8*)(pA + (size_t)(t * 16) * K + s * 32);
    pA += 64;

    const int niter = K >> 6;                      // 16 or 64: always even
    for (int it = 0; it < niter; it += 2) {
        __syncthreads();                           // Bs[0] + afa ready
        // prefetch for it+1: B -> Bs[1], A -> afb (drained by next barrier)
#pragma unroll
        for (int i = 0; i < 2; i++) {
            gload16(gb[i], Bs[1] + (i * 256 + w * 64) * 8);
            gb[i] += 64;
        }
#pragma unroll
        for (int s = 0; s < 2; s++)
#pragma unroll
            for (int t = 0; t < 2; t++)
                afb[s][t] = *(const bf16x8*)(pA + (size_t)(t * 16) * K + s * 32);
        pA += 64;

#pragma unroll
        for (int s = 0; s < 2; s++) {
            bf16x8 bfr[2];
#pragma unroll
            for (int t = 0; t < 2; t++)
                bfr[t] = *(const bf16x8*)((const char*)Bs[0] + offB[s][t]);
#pragma unroll
            for (int mt = 0; mt < 2; mt++)
#pragma unroll
                for (int nt = 0; nt < 2; nt++)
                    acc[mt][nt] = MFMA16(afa[s][mt], bfr[nt], acc[mt][nt]);
        }

        __syncthreads();                           // Bs[1] + afb ready
        if (it + 2 < niter) {
#pragma unroll
            for (int i = 0; i < 2; i++) {
                gload16(gb[i], Bs[0] + (i * 256 + w * 64) * 8);
                gb[i] += 64;
            }
#pragma unroll
            for (int s = 0; s < 2; s++)
#pragma unroll
                for (int t = 0; t < 2; t++)
                    afa[s][t] = *(const bf16x8*)(pA + (size_t)(t * 16) * K + s * 32);
            pA += 64;
        }

#pragma unroll
        for (int s = 0; s < 2; s++) {
            bf16x8 bfr[2];
#pragma unroll
            for (int t = 0; t < 2; t++)
                bfr[t] = *(const bf16x8*)((const char*)Bs[1] + offB[s][t]);
#pragma unroll
            for (int mt = 0; mt < 2; mt++)
#pragma unroll
                for (int nt = 0; nt < 2; nt++)
                    acc[mt][nt] = MFMA16(afb[s][mt], bfr[nt], acc[mt][nt]);
        }
    }

#pragma unroll
    for (int mt = 0; mt < 2; mt++)
#pragma unroll
        for (int nt = 0; nt < 2; nt++) {
            const int row = m0 + wm * 32 + mt * 16 + quad * 4;
            const int col = n0 + wn * 32 + nt * 16 + l16;
            const float bv = BIAS ? bias[col] : 0.0f;
#pragma unroll
            for (int r = 0; r < 4; r++) {
                float v = acc[mt][nt][r] + bv;
                if (RELU) v = v > 0.0f ? v : 0.0f;
                const size_t idx = (size_t)(row + r) * N + col;
                if (RESID) v += resid[idx];
                if (OUTBF) ((__hip_bfloat16*)out)[idx] = __float2bfloat16(v);
                else       ((float*)out)[idx] = v;
            }
        }
}

// ----------------------- V transpose: qkv -> Vt[bh][d][T] -------------------
__global__ __launch_bounds__(256) void vtrans_k(const __hip_bfloat16* __restrict__ qkv,
                                                __hip_bfloat16* __restrict__ vt) {
    const int T = 2048, C3 = 3072;
    const int bh = blockIdx.y, b = bh >> 4, h = bh & 15;
    const int t0 = blockIdx.x * 64;
    const int tx = threadIdx.x, ty = threadIdx.y;   // block (64, 4)
    __shared__ __hip_bfloat16 tile[64][65];
#pragma unroll
    for (int j = 0; j < 16; j++) {
        const int tl = ty * 16 + j;
        tile[tl][tx] = qkv[(size_t)(b * T + t0 + tl) * C3 + 2048 + h * 64 + tx];
    }
    __syncthreads();
#pragma unroll
    for (int j = 0; j < 16; j++) {
        const int d = ty * 16 + j;
        vt[((size_t)bh * 64 + d) * 2048 + t0 + tx] = tile[tx][d];
    }
}

// ------------------------------ flash attention -----------------------------
__global__ __launch_bounds__(256, 3) void attn_k(const __hip_bfloat16* __restrict__ qkv,
                                                 const __hip_bfloat16* __restrict__ vt,
                                                 __hip_bfloat16* __restrict__ outp) {
    const int T = 2048, C3 = 3072;
    const int bh = blockIdx.x, b = bh >> 4, h = bh & 15;
    const int qt = 31 - blockIdx.y;           // heavy q-tiles dispatched first
    const int q0 = qt * 64;
    const int tid = threadIdx.x, lane = tid & 63, w = tid >> 6;
    const int l16 = lane & 15, quad = lane >> 4;

    __align__(16) __shared__ __hip_bfloat16 Ks[2][64 * 64];   // swizzled [key][d]
    __align__(16) __shared__ __hip_bfloat16 Vs[2][64 * 64];   // swizzled [d][key]
    __align__(16) __shared__ __hip_bfloat16 Pw[4][16 * 72];   // per-wave P

    const float sc = 0.125f * 1.44269504f;
    bf16x8 qf0, qf1;
    {
        const __hip_bfloat16* qp =
            qkv + (size_t)(b * T + q0 + w * 16 + l16) * C3 + h * 64;
        bf16x8 a = *(const bf16x8*)(qp + quad * 8);
        bf16x8 c = *(const bf16x8*)(qp + 32 + quad * 8);
#pragma unroll
        for (int i = 0; i < 8; i++) {
            union { unsigned int u; float f; } ua, uc;
            ua.u = ((unsigned int)(unsigned short)a[i]) << 16;
            uc.u = ((unsigned int)(unsigned short)c[i]) << 16;
            qf0[i] = (short)(__bfloat16_as_ushort(__float2bfloat16(ua.f * sc)));
            qf1[i] = (short)(__bfloat16_as_ushort(__float2bfloat16(uc.f * sc)));
        }
    }

    const int srw = lane >> 3;
    const int scn = ((lane & 7) - srw) & 7;
    const __hip_bfloat16* kp[2];
    const __hip_bfloat16* vp[2];
#pragma unroll
    for (int i = 0; i < 2; i++) {
        const int row = i * 32 + w * 8 + srw;
        kp[i] = qkv + (size_t)(b * T + row) * C3 + 1024 + h * 64 + scn * 8;
        vp[i] = vt + ((size_t)bh * 64 + row) * 2048 + scn * 8;
    }

    int offK[2][4];
#pragma unroll
    for (int s = 0; s < 2; s++)
#pragma unroll
        for (int t = 0; t < 4; t++) {
            const int rr = t * 16 + l16;
            offK[s][t] = (rr * 8 + ((s * 4 + quad + (rr & 7)) & 7)) * 16;
        }

    f32x4 oacc[4] = {};
    float lpart[4] = {0.0f, 0.0f, 0.0f, 0.0f};

#pragma unroll
    for (int i = 0; i < 2; i++) {
        gload16(kp[i], Ks[0] + (i * 256 + w * 64) * 8);
        gload16(vp[i], Vs[0] + (i * 256 + w * 64) * 8);
    }

    for (int kt = 0; kt <= qt; kt++) {
        const int buf = kt & 1;
        __syncthreads();
        if (kt < qt) {
#pragma unroll
            for (int i = 0; i < 2; i++) {
                gload16(kp[i] + (size_t)(kt + 1) * 64 * C3,
                        Ks[buf ^ 1] + (i * 256 + w * 64) * 8);
                gload16(vp[i] + (kt + 1) * 64,
                        Vs[buf ^ 1] + (i * 256 + w * 64) * 8);
            }
        }

        f32x4 s4[4];
#pragma unroll
        for (int nt = 0; nt < 4; nt++) {
            bf16x8 kf0 = *(const bf16x8*)((const char*)Ks[buf] + offK[0][nt]);
            bf16x8 kf1 = *(const bf16x8*)((const char*)Ks[buf] + offK[1][nt]);
            f32x4 z = {};
            z = MFMA16(qf0, kf0, z);
            z = MFMA16(qf1, kf1, z);
            s4[nt] = z;
        }

        const bool diag = (kt == qt);
        const int myrow = w * 16 + quad * 4;
#pragma unroll
        for (int nt = 0; nt < 4; nt++) {
            const int col = nt * 16 + l16;
#pragma unroll
            for (int r = 0; r < 4; r++) {
                float p = exp2f(s4[nt][r]);
                if (diag && col > myrow + r) p = 0.0f;
                lpart[r] += p;
                Pw[w][(quad * 4 + r) * 72 + col] = __float2bfloat16(p);
            }
        }

        asm volatile("s_waitcnt lgkmcnt(0)" ::: "memory");

        bf16x8 pf0 = *(const bf16x8*)(&Pw[w][l16 * 72 + quad * 8]);
        bf16x8 pf1 = *(const bf16x8*)(&Pw[w][l16 * 72 + 32 + quad * 8]);
#pragma unroll
        for (int dt = 0; dt < 4; dt++) {
            bf16x8 vf0 = *(const bf16x8*)((const char*)Vs[buf] + offK[0][dt]);
            bf16x8 vf1 = *(const bf16x8*)((const char*)Vs[buf] + offK[1][dt]);
            oacc[dt] = MFMA16(pf0, vf0, oacc[dt]);
            oacc[dt] = MFMA16(pf1, vf1, oacc[dt]);
        }
    }

#pragma unroll
    for (int off = 1; off < 16; off <<= 1)
#pragma unroll
        for (int r = 0; r < 4; r++)
            lpart[r] += __shfl_xor(lpart[r], off, 64);

    float rl[4];
#pragma unroll
    for (int r = 0; r < 4; r++) rl[r] = 1.0f / lpart[r];
#pragma unroll
    for (int dt = 0; dt < 4; dt++)
#pragma unroll
        for (int r = 0; r < 4; r++) {
            const int row = q0 + w * 16 + quad * 4 + r;
            outp[(size_t)(b * T + row) * 1024 + h * 64 + dt * 16 + l16] =
                __float2bfloat16(oacc[dt][r] * rl[r]);
        }
}

// --------------------------------- launcher --------------------------------
extern "C" void kernel_launch(void* const* d_in, const int* in_sizes, int n_in,
                              void* d_out, int out_size, void* d_ws, size_t ws_size,
                              hipStream_t stream) {
    const float* x     = (const float*)d_in[0];
    const float* Wqkv  = (const float*)d_in[1];
    const float* Wo    = (const float*)d_in[2];
    const float* b_o   = (const float*)d_in[3];
    const float* g1    = (const float*)d_in[4];
    const float* beta1 = (const float*)d_in[5];
    const float* g2    = (const float*)d_in[6];
    const float* beta2 = (const float*)d_in[7];
    const float* Wff1  = (const float*)d_in[8];
    const float* bff1  = (const float*)d_in[9];
    const float* Wff2  = (const float*)d_in[10];
    const float* bff2  = (const float*)d_in[11];

    char* ws = (char*)d_ws;
    size_t off = 0;
    auto alloc = [&](size_t bytes) {
        void* p = ws + off;
        off += (bytes + 255) & ~(size_t)255;
        return p;
    };
    __hip_bfloat16* Wqkv_t = (__hip_bfloat16*)alloc(3072ULL * 1024 * 2);
    __hip_bfloat16* Wo_t   = (__hip_bfloat16*)alloc(1024ULL * 1024 * 2);
    __hip_bfloat16* Wff1_t = (__hip_bfloat16*)alloc(4096ULL * 1024 * 2);
    __hip_bfloat16* Wff2_t = (__hip_bfloat16*)alloc(1024ULL * 4096 * 2);
    __hip_bfloat16* h_bf   = (__hip_bfloat16*)alloc(4096ULL * 1024 * 2);
    __hip_bfloat16* qkv_bf = (__hip_bfloat16*)alloc(4096ULL * 3072 * 2);
    __hip_bfloat16* att_bf = (__hip_bfloat16*)alloc(4096ULL * 1024 * 2);
    float*          x2     = (float*)alloc(4096ULL * 1024 * 4);
    __hip_bfloat16* ff1_bf = qkv_bf;              // dead by FF time
    __hip_bfloat16* vt     = (__hip_bfloat16*)x2; // dead before Wo-gemm writes x2

    tconv_all<<<12288, dim3(32, 8), 0, stream>>>(Wqkv, Wqkv_t, Wo, Wo_t,
                                                 Wff1, Wff1_t, Wff2, Wff2_t);

    ln_k<<<4096, 256, 0, stream>>>(x, g1, beta1, h_bf);
    gemm_k<0, 0, 0, 1><<<dim3(3072 / 128, 4096 / 128), 256, 0, stream>>>(
        h_bf, Wqkv_t, nullptr, nullptr, qkv_bf, 4096, 3072, 1024);
    vtrans_k<<<dim3(32, 32), dim3(64, 4), 0, stream>>>(qkv_bf, vt);
    attn_k<<<dim3(32, 32), 256, 0, stream>>>(qkv_bf, vt, att_bf);
    gemm_flat_k<1, 0, 1, 0><<<dim3(1024 / 64, 4096 / 64), 256, 0, stream>>>(
        att_bf, Wo_t, b_o, x, x2, 4096, 1024, 1024);
    ln_k<<<4096, 256, 0, stream>>>(x2, g2, beta2, h_bf);
    gemm_k<1, 1, 0, 1><<<dim3(4096 / 128, 4096 / 128), 256, 0, stream>>>(
        h_bf, Wff1_t, bff1, nullptr, ff1_bf, 4096, 4096, 1024);
    gemm_flat_k<1, 0, 1, 0><<<dim3(1024 / 64, 4096 / 64), 256, 0, stream>>>(
        ff1_bf, Wff2_t, bff2, x2, (float*)d_out, 4096, 1024, 4096);
}

// Round 6
// 362.487 us; speedup vs baseline: 1.2044x; 1.2044x over previous
//
#include <hip/hip_runtime.h>
#include <hip/hip_bf16.h>
#include <stdint.h>

// ---------------------------------------------------------------------------
// TransformerDecoderBlock on MI355X (gfx950).  B=2, T=2048, C=1024, H=16, hd=64.
// R8:  64^2 tiles for N=1024 GEMMs, 16 waves/CU, drain-0 dbuf.   [best: 325.7us]
// R9:  ring + counted vmcnt, RUNTIME buf idx -> codegen death (VGPR+24). Sync
//      design passed correctness.
// R10/R11: bigger tiles -> occupancy loss dominates. R12: BK=32 swizzle ->
//      4.2M bank conflicts. R13: A-from-global flatmm -> latency stall
//      (issue->consume ~50cy vs 200-900cy mem latency), 147us.
// R14: R9's sync + R8's codegen = STATIC unroll-3 ring. 3 buffers, loop
//      stepped by 3, phase macro with compile-time BUF/PRE. wait vmcnt(4)
//      (never 0 mid-loop) + raw s_barrier; depth-2 prefetch gives each load
//      a full extra iteration to land. LDS 48KB -> 3 blocks/CU (12 waves).
//      Everything else = R8 verbatim.
// ---------------------------------------------------------------------------

typedef __attribute__((ext_vector_type(8))) short bf16x8;   // 8 bf16 in 4 VGPRs
typedef __attribute__((ext_vector_type(4))) float f32x4;

#define MFMA16(a, b, c) __builtin_amdgcn_mfma_f32_16x16x32_bf16((a), (b), (c), 0, 0, 0)

__device__ __forceinline__ void gload16(const void* g, void* l) {
    __builtin_amdgcn_global_load_lds(
        (const __attribute__((address_space(1))) char*)g,
        (__attribute__((address_space(3))) char*)l, 16, 0, 0);
}

// XCD-aware remap: contiguous chunk of work per XCD (XCD = dispatch id % 8).
__device__ __forceinline__ int xcd_swizzle(int flat, int nblk) {
    if ((nblk & 7) == 0) {
        const int per = nblk >> 3;
        flat = (flat & 7) * per + (flat >> 3);
    }
    return flat;
}

// ---------------- merged transpose + fp32->bf16 for all 4 weights -----------
__global__ __launch_bounds__(256) void tconv_all(
    const float* __restrict__ w0, __hip_bfloat16* __restrict__ o0,   // 1024x3072
    const float* __restrict__ w1, __hip_bfloat16* __restrict__ o1,   // 1024x1024
    const float* __restrict__ w2, __hip_bfloat16* __restrict__ o2,   // 1024x4096
    const float* __restrict__ w3, __hip_bfloat16* __restrict__ o3) { // 4096x1024
    __shared__ float tile[32][33];
    const int f = blockIdx.x;
    const float* in; __hip_bfloat16* out; int K, N, nx, t;
    if (f < 3072)      { in = w0; out = o0; K = 1024; N = 3072; nx = 96;  t = f; }
    else if (f < 4096) { in = w1; out = o1; K = 1024; N = 1024; nx = 32;  t = f - 3072; }
    else if (f < 8192) { in = w2; out = o2; K = 1024; N = 4096; nx = 128; t = f - 4096; }
    else               { in = w3; out = o3; K = 4096; N = 1024; nx = 32;  t = f - 8192; }
    const int n0 = (t % nx) * 32, k0 = (t / nx) * 32;
    const int tx = threadIdx.x, ty = threadIdx.y;   // block (32, 8)
    for (int i = ty; i < 32; i += 8)
        tile[i][tx] = in[(size_t)(k0 + i) * N + n0 + tx];
    __syncthreads();
    for (int i = ty; i < 32; i += 8)
        out[(size_t)(n0 + i) * K + k0 + tx] = __float2bfloat16(tile[tx][i]);
}

// --------------------------------- layernorm -------------------------------
__global__ __launch_bounds__(256) void ln_k(const float* __restrict__ x,
                                            const float* __restrict__ g,
                                            const float* __restrict__ beta,
                                            __hip_bfloat16* __restrict__ out) {
    const int row = blockIdx.x;
    const int tid = threadIdx.x;
    float4 v = ((const float4*)(x + (size_t)row * 1024))[tid];
    float s  = v.x + v.y + v.z + v.w;
    float s2 = v.x * v.x + v.y * v.y + v.z * v.z + v.w * v.w;
    for (int off = 1; off < 64; off <<= 1) {
        s  += __shfl_xor(s,  off, 64);
        s2 += __shfl_xor(s2, off, 64);
    }
    __shared__ float ss[4], ss2[4];
    const int w = tid >> 6, lane = tid & 63;
    if (lane == 0) { ss[w] = s; ss2[w] = s2; }
    __syncthreads();
    s  = ss[0] + ss[1] + ss[2] + ss[3];
    s2 = ss2[0] + ss2[1] + ss2[2] + ss2[3];
    const float mu  = s * (1.0f / 1024.0f);
    const float var = s2 * (1.0f / 1024.0f) - mu * mu;
    const float rs  = rsqrtf(var + 1e-5f);
    float4 gv = ((const float4*)g)[tid];
    float4 bv = ((const float4*)beta)[tid];
    __hip_bfloat16* o = out + (size_t)row * 1024 + tid * 4;
    o[0] = __float2bfloat16((v.x - mu) * rs * gv.x + bv.x);
    o[1] = __float2bfloat16((v.y - mu) * rs * gv.y + bv.y);
    o[2] = __float2bfloat16((v.z - mu) * rs * gv.z + bv.z);
    o[3] = __float2bfloat16((v.w - mu) * rs * gv.w + bv.w);
}

// ------------------- GEMM, BM=128 BN=128 BK=64, dbuf 1-barrier ---------------
template <int BIAS, int RELU, int RESID, int OUTBF>
__global__ __launch_bounds__(256, 2) void gemm_k(const __hip_bfloat16* __restrict__ A,
                                                 const __hip_bfloat16* __restrict__ Bt,
                                                 const float* __restrict__ bias,
                                                 const float* __restrict__ resid,
                                                 void* __restrict__ out,
                                                 int M, int N, int K) {
    __align__(16) __shared__ __hip_bfloat16 As[2][128 * 64];
    __align__(16) __shared__ __hip_bfloat16 Bs[2][128 * 64];

    const int tid  = threadIdx.x;
    const int lane = tid & 63, w = tid >> 6;
    const int wm = w >> 1, wn = w & 1;
    const int nbx = gridDim.x;
    const int flat = xcd_swizzle(blockIdx.y * nbx + blockIdx.x, nbx * gridDim.y);
    const int m0 = (flat / nbx) * 128, n0 = (flat % nbx) * 128;
    const int l16 = lane & 15, quad = lane >> 4;

    const int srw = lane >> 3;                 // 0..7
    const int scn = ((lane & 7) - srw) & 7;    // source chunk (swizzled)

    const __hip_bfloat16* ga[4];
    const __hip_bfloat16* gb[4];
#pragma unroll
    for (int i = 0; i < 4; i++) {
        const int row = i * 32 + w * 8 + srw;
        ga[i] = A  + (size_t)(m0 + row) * K + scn * 8;
        gb[i] = Bt + (size_t)(n0 + row) * K + scn * 8;
    }

    int offA[2][4], offB[2][4];
#pragma unroll
    for (int s = 0; s < 2; s++)
#pragma unroll
        for (int t = 0; t < 4; t++) {
            const int rA = wm * 64 + t * 16 + l16;
            offA[s][t] = (rA * 8 + ((s * 4 + quad + (rA & 7)) & 7)) * 16;
            const int rB = wn * 64 + t * 16 + l16;
            offB[s][t] = (rB * 8 + ((s * 4 + quad + (rB & 7)) & 7)) * 16;
        }

    f32x4 acc[4][4] = {};

#pragma unroll
    for (int i = 0; i < 4; i++) {
        gload16(ga[i], As[0] + (i * 256 + w * 64) * 8);
        gload16(gb[i], Bs[0] + (i * 256 + w * 64) * 8);
        ga[i] += 64; gb[i] += 64;
    }

    const int niter = K >> 6;
    for (int it = 0; it < niter; it++) {
        const int buf = it & 1;
        __syncthreads();   // drains prefetch into buf (issued prev iter)
        if (it + 1 < niter) {
#pragma unroll
            for (int i = 0; i < 4; i++) {
                gload16(ga[i], As[buf ^ 1] + (i * 256 + w * 64) * 8);
                gload16(gb[i], Bs[buf ^ 1] + (i * 256 + w * 64) * 8);
                ga[i] += 64; gb[i] += 64;
            }
        }

#pragma unroll
        for (int s = 0; s < 2; s++) {
            bf16x8 af[4], bfr[4];
#pragma unroll
            for (int t = 0; t < 4; t++) {
                af[t]  = *(const bf16x8*)((const char*)As[buf] + offA[s][t]);
                bfr[t] = *(const bf16x8*)((const char*)Bs[buf] + offB[s][t]);
            }
#pragma unroll
            for (int mt = 0; mt < 4; mt++)
#pragma unroll
                for (int nt = 0; nt < 4; nt++)
                    acc[mt][nt] = MFMA16(af[mt], bfr[nt], acc[mt][nt]);
        }
    }

#pragma unroll
    for (int mt = 0; mt < 4; mt++)
#pragma unroll
        for (int nt = 0; nt < 4; nt++) {
            const int row = m0 + wm * 64 + mt * 16 + quad * 4;
            const int col = n0 + wn * 64 + nt * 16 + l16;
            const float bv = BIAS ? bias[col] : 0.0f;
#pragma unroll
            for (int r = 0; r < 4; r++) {
                float v = acc[mt][nt][r] + bv;
                if (RELU) v = v > 0.0f ? v : 0.0f;
                const size_t idx = (size_t)(row + r) * N + col;
                if (RESID) v += resid[idx];
                if (OUTBF) ((__hip_bfloat16*)out)[idx] = __float2bfloat16(v);
                else       ((float*)out)[idx] = v;
            }
        }
}

// -------- GEMM, BM=64 BN=64 BK=64, STATIC 3-buffer ring, counted vmcnt ------
// R14: R9's (correctness-proven) sync with R8's codegen. Loop stepped by 3,
// phase macro with COMPILE-TIME buffer indices. Per phase: wait vmcnt(4)
// (tile T done, T+1 in flight) -> s_barrier -> prefetch T+2 -> compute T.
// Depth-2 prefetch: each load gets ~2 iterations to land. LDS 48KB -> 3/CU.
template <int BIAS, int RELU, int RESID, int OUTBF>
__global__ __launch_bounds__(256, 3) void gemm6464_k(const __hip_bfloat16* __restrict__ A,
                                                     const __hip_bfloat16* __restrict__ Bt,
                                                     const float* __restrict__ bias,
                                                     const float* __restrict__ resid,
                                                     void* __restrict__ out,
                                                     int M, int N, int K) {
    __align__(16) __shared__ __hip_bfloat16 As[3][64 * 64];
    __align__(16) __shared__ __hip_bfloat16 Bs[3][64 * 64];

    const int tid  = threadIdx.x;
    const int lane = tid & 63, w = tid >> 6;
    const int wm = w >> 1, wn = w & 1;             // 2x2 wave grid of 32x32
    const int nbx = gridDim.x;
    const int flat = xcd_swizzle(blockIdx.y * nbx + blockIdx.x, nbx * gridDim.y);
    const int m0 = (flat / nbx) * 64, n0 = (flat % nbx) * 64;
    const int l16 = lane & 15, quad = lane >> 4;

    const int srw = lane >> 3;
    const int scn = ((lane & 7) - srw) & 7;

    const __hip_bfloat16* ga[2];
    const __hip_bfloat16* gb[2];
#pragma unroll
    for (int i = 0; i < 2; i++) {
        const int row = i * 32 + w * 8 + srw;
        ga[i] = A  + (size_t)(m0 + row) * K + scn * 8;
        gb[i] = Bt + (size_t)(n0 + row) * K + scn * 8;
    }

    int offA[2][2], offB[2][2];
#pragma unroll
    for (int s = 0; s < 2; s++)
#pragma unroll
        for (int t = 0; t < 2; t++) {
            const int rA = wm * 32 + t * 16 + l16;
            offA[s][t] = (rA * 8 + ((s * 4 + quad + (rA & 7)) & 7)) * 16;
            const int rB = wn * 32 + t * 16 + l16;
            offB[s][t] = (rB * 8 + ((s * 4 + quad + (rB & 7)) & 7)) * 16;
        }

    f32x4 acc[2][2] = {};

    const int niter = K >> 6;                      // 16 (Wo) or 64 (FF2), >= 2

    // prologue: stage tiles 0 and 1 (8 gload16 in flight per wave)
#pragma unroll
    for (int i = 0; i < 2; i++) {
        gload16(ga[i], As[0] + (i * 256 + w * 64) * 8);
        gload16(gb[i], Bs[0] + (i * 256 + w * 64) * 8);
        ga[i] += 64; gb[i] += 64;
    }
#pragma unroll
    for (int i = 0; i < 2; i++) {
        gload16(ga[i], As[1] + (i * 256 + w * 64) * 8);
        gload16(gb[i], Bs[1] + (i * 256 + w * 64) * 8);
        ga[i] += 64; gb[i] += 64;
    }

    // Phase T (BUF = T%3 compile-time, PRE = (T+2)%3):
    //   wait vmcnt(4): tile T's 4 loads done (T+1's stay in flight);
    //   barrier: all waves' tile-T loads landed; buf PRE's phase-(T-1)
    //     ds_reads completed (MFMA consumption) before any wave arrived;
    //   prefetch tile T+2 into PRE; compute tile T from BUF.
#define GPHASE(T, BUF, PRE)                                                   \
    do {                                                                      \
        if ((T) + 1 < niter) asm volatile("s_waitcnt vmcnt(4)" ::: "memory"); \
        else                 asm volatile("s_waitcnt vmcnt(0)" ::: "memory"); \
        __builtin_amdgcn_s_barrier();                                         \
        asm volatile("" ::: "memory");                                        \
        if ((T) + 2 < niter) {                                                \
            _Pragma("unroll")                                                 \
            for (int i = 0; i < 2; i++) {                                     \
                gload16(ga[i], As[PRE] + (i * 256 + w * 64) * 8);             \
                gload16(gb[i], Bs[PRE] + (i * 256 + w * 64) * 8);             \
                ga[i] += 64; gb[i] += 64;                                     \
            }                                                                 \
        }                                                                     \
        _Pragma("unroll")                                                     \
        for (int s = 0; s < 2; s++) {                                         \
            bf16x8 af[2], bfr[2];                                             \
            _Pragma("unroll")                                                 \
            for (int t = 0; t < 2; t++) {                                     \
                af[t]  = *(const bf16x8*)((const char*)As[BUF] + offA[s][t]); \
                bfr[t] = *(const bf16x8*)((const char*)Bs[BUF] + offB[s][t]); \
            }                                                                 \
            _Pragma("unroll")                                                 \
            for (int mt = 0; mt < 2; mt++)                                    \
                _Pragma("unroll")                                             \
                for (int nt = 0; nt < 2; nt++)                                \
                    acc[mt][nt] = MFMA16(af[mt], bfr[nt], acc[mt][nt]);       \
        }                                                                     \
    } while (0)

    for (int t3 = 0; t3 < niter; t3 += 3) {
        GPHASE(t3, 0, 2);
        if (t3 + 1 < niter) GPHASE(t3 + 1, 1, 0);
        if (t3 + 2 < niter) GPHASE(t3 + 2, 2, 1);
    }
#undef GPHASE

#pragma unroll
    for (int mt = 0; mt < 2; mt++)
#pragma unroll
        for (int nt = 0; nt < 2; nt++) {
            const int row = m0 + wm * 32 + mt * 16 + quad * 4;
            const int col = n0 + wn * 32 + nt * 16 + l16;
            const float bv = BIAS ? bias[col] : 0.0f;
#pragma unroll
            for (int r = 0; r < 4; r++) {
                float v = acc[mt][nt][r] + bv;
                if (RELU) v = v > 0.0f ? v : 0.0f;
                const size_t idx = (size_t)(row + r) * N + col;
                if (RESID) v += resid[idx];
                if (OUTBF) ((__hip_bfloat16*)out)[idx] = __float2bfloat16(v);
                else       ((float*)out)[idx] = v;
            }
        }
}

// ----------------------- V transpose: qkv -> Vt[bh][d][T] -------------------
__global__ __launch_bounds__(256) void vtrans_k(const __hip_bfloat16* __restrict__ qkv,
                                                __hip_bfloat16* __restrict__ vt) {
    const int T = 2048, C3 = 3072;
    const int bh = blockIdx.y, b = bh >> 4, h = bh & 15;
    const int t0 = blockIdx.x * 64;
    const int tx = threadIdx.x, ty = threadIdx.y;   // block (64, 4)
    __shared__ __hip_bfloat16 tile[64][65];
#pragma unroll
    for (int j = 0; j < 16; j++) {
        const int tl = ty * 16 + j;
        tile[tl][tx] = qkv[(size_t)(b * T + t0 + tl) * C3 + 2048 + h * 64 + tx];
    }
    __syncthreads();
#pragma unroll
    for (int j = 0; j < 16; j++) {
        const int d = ty * 16 + j;
        vt[((size_t)bh * 64 + d) * 2048 + t0 + tx] = tile[tx][d];
    }
}

// ------------------------------ flash attention -----------------------------
__global__ __launch_bounds__(256, 3) void attn_k(const __hip_bfloat16* __restrict__ qkv,
                                                 const __hip_bfloat16* __restrict__ vt,
                                                 __hip_bfloat16* __restrict__ outp) {
    const int T = 2048, C3 = 3072;
    const int bh = blockIdx.x, b = bh >> 4, h = bh & 15;
    const int qt = 31 - blockIdx.y;           // heavy q-tiles dispatched first
    const int q0 = qt * 64;
    const int tid = threadIdx.x, lane = tid & 63, w = tid >> 6;
    const int l16 = lane & 15, quad = lane >> 4;

    __align__(16) __shared__ __hip_bfloat16 Ks[2][64 * 64];   // swizzled [key][d]
    __align__(16) __shared__ __hip_bfloat16 Vs[2][64 * 64];   // swizzled [d][key]
    __align__(16) __shared__ __hip_bfloat16 Pw[4][16 * 72];   // per-wave P

    const float sc = 0.125f * 1.44269504f;
    bf16x8 qf0, qf1;
    {
        const __hip_bfloat16* qp =
            qkv + (size_t)(b * T + q0 + w * 16 + l16) * C3 + h * 64;
        bf16x8 a = *(const bf16x8*)(qp + quad * 8);
        bf16x8 c = *(const bf16x8*)(qp + 32 + quad * 8);
#pragma unroll
        for (int i = 0; i < 8; i++) {
            union { unsigned int u; float f; } ua, uc;
            ua.u = ((unsigned int)(unsigned short)a[i]) << 16;
            uc.u = ((unsigned int)(unsigned short)c[i]) << 16;
            qf0[i] = (short)(__bfloat16_as_ushort(__float2bfloat16(ua.f * sc)));
            qf1[i] = (short)(__bfloat16_as_ushort(__float2bfloat16(uc.f * sc)));
        }
    }

    const int srw = lane >> 3;
    const int scn = ((lane & 7) - srw) & 7;
    const __hip_bfloat16* kp[2];
    const __hip_bfloat16* vp[2];
#pragma unroll
    for (int i = 0; i < 2; i++) {
        const int row = i * 32 + w * 8 + srw;
        kp[i] = qkv + (size_t)(b * T + row) * C3 + 1024 + h * 64 + scn * 8;
        vp[i] = vt + ((size_t)bh * 64 + row) * 2048 + scn * 8;
    }

    int offK[2][4];
#pragma unroll
    for (int s = 0; s < 2; s++)
#pragma unroll
        for (int t = 0; t < 4; t++) {
            const int rr = t * 16 + l16;
            offK[s][t] = (rr * 8 + ((s * 4 + quad + (rr & 7)) & 7)) * 16;
        }

    f32x4 oacc[4] = {};
    float lpart[4] = {0.0f, 0.0f, 0.0f, 0.0f};

#pragma unroll
    for (int i = 0; i < 2; i++) {
        gload16(kp[i], Ks[0] + (i * 256 + w * 64) * 8);
        gload16(vp[i], Vs[0] + (i * 256 + w * 64) * 8);
    }

    for (int kt = 0; kt <= qt; kt++) {
        const int buf = kt & 1;
        __syncthreads();
        if (kt < qt) {
#pragma unroll
            for (int i = 0; i < 2; i++) {
                gload16(kp[i] + (size_t)(kt + 1) * 64 * C3,
                        Ks[buf ^ 1] + (i * 256 + w * 64) * 8);
                gload16(vp[i] + (kt + 1) * 64,
                        Vs[buf ^ 1] + (i * 256 + w * 64) * 8);
            }
        }

        f32x4 s4[4];
#pragma unroll
        for (int nt = 0; nt < 4; nt++) {
            bf16x8 kf0 = *(const bf16x8*)((const char*)Ks[buf] + offK[0][nt]);
            bf16x8 kf1 = *(const bf16x8*)((const char*)Ks[buf] + offK[1][nt]);
            f32x4 z = {};
            z = MFMA16(qf0, kf0, z);
            z = MFMA16(qf1, kf1, z);
            s4[nt] = z;
        }

        const bool diag = (kt == qt);
        const int myrow = w * 16 + quad * 4;
#pragma unroll
        for (int nt = 0; nt < 4; nt++) {
            const int col = nt * 16 + l16;
#pragma unroll
            for (int r = 0; r < 4; r++) {
                float p = exp2f(s4[nt][r]);
                if (diag && col > myrow + r) p = 0.0f;
                lpart[r] += p;
                Pw[w][(quad * 4 + r) * 72 + col] = __float2bfloat16(p);
            }
        }

        asm volatile("s_waitcnt lgkmcnt(0)" ::: "memory");

        bf16x8 pf0 = *(const bf16x8*)(&Pw[w][l16 * 72 + quad * 8]);
        bf16x8 pf1 = *(const bf16x8*)(&Pw[w][l16 * 72 + 32 + quad * 8]);
#pragma unroll
        for (int dt = 0; dt < 4; dt++) {
            bf16x8 vf0 = *(const bf16x8*)((const char*)Vs[buf] + offK[0][dt]);
            bf16x8 vf1 = *(const bf16x8*)((const char*)Vs[buf] + offK[1][dt]);
            oacc[dt] = MFMA16(pf0, vf0, oacc[dt]);
            oacc[dt] = MFMA16(pf1, vf1, oacc[dt]);
        }
    }

#pragma unroll
    for (int off = 1; off < 16; off <<= 1)
#pragma unroll
        for (int r = 0; r < 4; r++)
            lpart[r] += __shfl_xor(lpart[r], off, 64);

    float rl[4];
#pragma unroll
    for (int r = 0; r < 4; r++) rl[r] = 1.0f / lpart[r];
#pragma unroll
    for (int dt = 0; dt < 4; dt++)
#pragma unroll
        for (int r = 0; r < 4; r++) {
            const int row = q0 + w * 16 + quad * 4 + r;
            outp[(size_t)(b * T + row) * 1024 + h * 64 + dt * 16 + l16] =
                __float2bfloat16(oacc[dt][r] * rl[r]);
        }
}

// --------------------------------- launcher --------------------------------
extern "C" void kernel_launch(void* const* d_in, const int* in_sizes, int n_in,
                              void* d_out, int out_size, void* d_ws, size_t ws_size,
                              hipStream_t stream) {
    const float* x     = (const float*)d_in[0];
    const float* Wqkv  = (const float*)d_in[1];
    const float* Wo    = (const float*)d_in[2];
    const float* b_o   = (const float*)d_in[3];
    const float* g1    = (const float*)d_in[4];
    const float* beta1 = (const float*)d_in[5];
    const float* g2    = (const float*)d_in[6];
    const float* beta2 = (const float*)d_in[7];
    const float* Wff1  = (const float*)d_in[8];
    const float* bff1  = (const float*)d_in[9];
    const float* Wff2  = (const float*)d_in[10];
    const float* bff2  = (const float*)d_in[11];

    char* ws = (char*)d_ws;
    size_t off = 0;
    auto alloc = [&](size_t bytes) {
        void* p = ws + off;
        off += (bytes + 255) & ~(size_t)255;
        return p;
    };
    __hip_bfloat16* Wqkv_t = (__hip_bfloat16*)alloc(3072ULL * 1024 * 2);
    __hip_bfloat16* Wo_t   = (__hip_bfloat16*)alloc(1024ULL * 1024 * 2);
    __hip_bfloat16* Wff1_t = (__hip_bfloat16*)alloc(4096ULL * 1024 * 2);
    __hip_bfloat16* Wff2_t = (__hip_bfloat16*)alloc(1024ULL * 4096 * 2);
    __hip_bfloat16* h_bf   = (__hip_bfloat16*)alloc(4096ULL * 1024 * 2);
    __hip_bfloat16* qkv_bf = (__hip_bfloat16*)alloc(4096ULL * 3072 * 2);
    __hip_bfloat16* att_bf = (__hip_bfloat16*)alloc(4096ULL * 1024 * 2);
    float*          x2     = (float*)alloc(4096ULL * 1024 * 4);
    __hip_bfloat16* ff1_bf = qkv_bf;              // dead by FF time
    __hip_bfloat16* vt     = (__hip_bfloat16*)x2; // dead before Wo-gemm writes x2

    tconv_all<<<12288, dim3(32, 8), 0, stream>>>(Wqkv, Wqkv_t, Wo, Wo_t,
                                                 Wff1, Wff1_t, Wff2, Wff2_t);

    ln_k<<<4096, 256, 0, stream>>>(x, g1, beta1, h_bf);
    gemm_k<0, 0, 0, 1><<<dim3(3072 / 128, 4096 / 128), 256, 0, stream>>>(
        h_bf, Wqkv_t, nullptr, nullptr, qkv_bf, 4096, 3072, 1024);
    vtrans_k<<<dim3(32, 32), dim3(64, 4), 0, stream>>>(qkv_bf, vt);
    attn_k<<<dim3(32, 32), 256, 0, stream>>>(qkv_bf, vt, att_bf);
    gemm6464_k<1, 0, 1, 0><<<dim3(1024 / 64, 4096 / 64), 256, 0, stream>>>(
        att_bf, Wo_t, b_o, x, x2, 4096, 1024, 1024);
    ln_k<<<4096, 256, 0, stream>>>(x2, g2, beta2, h_bf);
    gemm_k<1, 1, 0, 1><<<dim3(4096 / 128, 4096 / 128), 256, 0, stream>>>(
        h_bf, Wff1_t, bff1, nullptr, ff1_bf, 4096, 4096, 1024);
    gemm6464_k<1, 0, 1, 0><<<dim3(1024 / 64, 4096 / 64), 256, 0, stream>>>(
        ff1_bf, Wff2_t, bff2, x2, (float*)d_out, 4096, 1024, 4096);
}

// Round 7
// 315.112 us; speedup vs baseline: 1.3854x; 1.1503x over previous
//
#include <hip/hip_runtime.h>
#include <hip/hip_bf16.h>
#include <stdint.h>

// ---------------------------------------------------------------------------
// TransformerDecoderBlock on MI355X (gfx950).  B=2, T=2048, C=1024, H=16, hd=64.
// R8  (champion, 325.7us): 128^2 gemm_k for qkv/FF1 (2 blk/CU), 64^2
//      gemm6464_k for Wo/FF2 (4 blk/CU, 16 waves, drain-0 dbuf).
// R9-R14 all FAILED (334-437us): counted-vmcnt rings (R9/R14 ~equal -> the
//      SCHEME regresses, not codegen; matches guide m131-m141), bigger tiles
//      (occupancy loss), BK=32 swizzle (bank conflicts), A-from-global
//      (latency stall). Structure frozen at R8.
// R15: R8 restored verbatim + ONE isolated fix: tconv_all 32x64 tiles with
//      packed uint32 (2xbf16) writes -> 128B coalesced write segments
//      (was 64B half-lines). Pure-BW kernel, no sync changes.
// ---------------------------------------------------------------------------

typedef __attribute__((ext_vector_type(8))) short bf16x8;   // 8 bf16 in 4 VGPRs
typedef __attribute__((ext_vector_type(4))) float f32x4;

#define MFMA16(a, b, c) __builtin_amdgcn_mfma_f32_16x16x32_bf16((a), (b), (c), 0, 0, 0)

__device__ __forceinline__ void gload16(const void* g, void* l) {
    __builtin_amdgcn_global_load_lds(
        (const __attribute__((address_space(1))) char*)g,
        (__attribute__((address_space(3))) char*)l, 16, 0, 0);
}

// XCD-aware remap: contiguous chunk of work per XCD (XCD = dispatch id % 8).
__device__ __forceinline__ int xcd_swizzle(int flat, int nblk) {
    if ((nblk & 7) == 0) {
        const int per = nblk >> 3;
        flat = (flat & 7) * per + (flat >> 3);
    }
    return flat;
}

// ---------------- merged transpose + fp32->bf16 for all 4 weights -----------
// R15: 32(n) x 64(k) tiles; writes packed 2xbf16 -> 128B segments.
__global__ __launch_bounds__(256) void tconv_all(
    const float* __restrict__ w0, __hip_bfloat16* __restrict__ o0,   // 1024x3072
    const float* __restrict__ w1, __hip_bfloat16* __restrict__ o1,   // 1024x1024
    const float* __restrict__ w2, __hip_bfloat16* __restrict__ o2,   // 1024x4096
    const float* __restrict__ w3, __hip_bfloat16* __restrict__ o3) { // 4096x1024
    __shared__ float tile[64][33];                  // [k][n]
    const int f = blockIdx.x;
    const float* in; __hip_bfloat16* out; int K, N, nx, t;
    if (f < 1536)      { in = w0; out = o0; K = 1024; N = 3072; nx = 96;  t = f; }
    else if (f < 2048) { in = w1; out = o1; K = 1024; N = 1024; nx = 32;  t = f - 1536; }
    else if (f < 4096) { in = w2; out = o2; K = 1024; N = 4096; nx = 128; t = f - 2048; }
    else               { in = w3; out = o3; K = 4096; N = 1024; nx = 32;  t = f - 4096; }
    const int n0 = (t % nx) * 32, k0 = (t / nx) * 64;
    const int tx = threadIdx.x, ty = threadIdx.y;   // block (32, 8)
#pragma unroll
    for (int i = 0; i < 8; i++)
        tile[i * 8 + ty][tx] = in[(size_t)(k0 + i * 8 + ty) * N + n0 + tx];
    __syncthreads();
    // lane tx writes k-pair (2tx, 2tx+1) of row n0+i: 32 lanes x 4B = 128B.
    for (int i = ty; i < 32; i += 8) {
        const unsigned short lo =
            __bfloat16_as_ushort(__float2bfloat16(tile[2 * tx][i]));
        const unsigned short hi =
            __bfloat16_as_ushort(__float2bfloat16(tile[2 * tx + 1][i]));
        *(uint32_t*)(out + (size_t)(n0 + i) * K + k0 + 2 * tx) =
            ((uint32_t)hi << 16) | lo;
    }
}

// --------------------------------- layernorm -------------------------------
__global__ __launch_bounds__(256) void ln_k(const float* __restrict__ x,
                                            const float* __restrict__ g,
                                            const float* __restrict__ beta,
                                            __hip_bfloat16* __restrict__ out) {
    const int row = blockIdx.x;
    const int tid = threadIdx.x;
    float4 v = ((const float4*)(x + (size_t)row * 1024))[tid];
    float s  = v.x + v.y + v.z + v.w;
    float s2 = v.x * v.x + v.y * v.y + v.z * v.z + v.w * v.w;
    for (int off = 1; off < 64; off <<= 1) {
        s  += __shfl_xor(s,  off, 64);
        s2 += __shfl_xor(s2, off, 64);
    }
    __shared__ float ss[4], ss2[4];
    const int w = tid >> 6, lane = tid & 63;
    if (lane == 0) { ss[w] = s; ss2[w] = s2; }
    __syncthreads();
    s  = ss[0] + ss[1] + ss[2] + ss[3];
    s2 = ss2[0] + ss2[1] + ss2[2] + ss2[3];
    const float mu  = s * (1.0f / 1024.0f);
    const float var = s2 * (1.0f / 1024.0f) - mu * mu;
    const float rs  = rsqrtf(var + 1e-5f);
    float4 gv = ((const float4*)g)[tid];
    float4 bv = ((const float4*)beta)[tid];
    __hip_bfloat16* o = out + (size_t)row * 1024 + tid * 4;
    o[0] = __float2bfloat16((v.x - mu) * rs * gv.x + bv.x);
    o[1] = __float2bfloat16((v.y - mu) * rs * gv.y + bv.y);
    o[2] = __float2bfloat16((v.z - mu) * rs * gv.z + bv.z);
    o[3] = __float2bfloat16((v.w - mu) * rs * gv.w + bv.w);
}

// ------------------- GEMM, BM=128 BN=128 BK=64, dbuf 1-barrier ---------------
template <int BIAS, int RELU, int RESID, int OUTBF>
__global__ __launch_bounds__(256, 2) void gemm_k(const __hip_bfloat16* __restrict__ A,
                                                 const __hip_bfloat16* __restrict__ Bt,
                                                 const float* __restrict__ bias,
                                                 const float* __restrict__ resid,
                                                 void* __restrict__ out,
                                                 int M, int N, int K) {
    __align__(16) __shared__ __hip_bfloat16 As[2][128 * 64];
    __align__(16) __shared__ __hip_bfloat16 Bs[2][128 * 64];

    const int tid  = threadIdx.x;
    const int lane = tid & 63, w = tid >> 6;
    const int wm = w >> 1, wn = w & 1;
    const int nbx = gridDim.x;
    const int flat = xcd_swizzle(blockIdx.y * nbx + blockIdx.x, nbx * gridDim.y);
    const int m0 = (flat / nbx) * 128, n0 = (flat % nbx) * 128;
    const int l16 = lane & 15, quad = lane >> 4;

    const int srw = lane >> 3;                 // 0..7
    const int scn = ((lane & 7) - srw) & 7;    // source chunk (swizzled)

    const __hip_bfloat16* ga[4];
    const __hip_bfloat16* gb[4];
#pragma unroll
    for (int i = 0; i < 4; i++) {
        const int row = i * 32 + w * 8 + srw;
        ga[i] = A  + (size_t)(m0 + row) * K + scn * 8;
        gb[i] = Bt + (size_t)(n0 + row) * K + scn * 8;
    }

    int offA[2][4], offB[2][4];
#pragma unroll
    for (int s = 0; s < 2; s++)
#pragma unroll
        for (int t = 0; t < 4; t++) {
            const int rA = wm * 64 + t * 16 + l16;
            offA[s][t] = (rA * 8 + ((s * 4 + quad + (rA & 7)) & 7)) * 16;
            const int rB = wn * 64 + t * 16 + l16;
            offB[s][t] = (rB * 8 + ((s * 4 + quad + (rB & 7)) & 7)) * 16;
        }

    f32x4 acc[4][4] = {};

#pragma unroll
    for (int i = 0; i < 4; i++) {
        gload16(ga[i], As[0] + (i * 256 + w * 64) * 8);
        gload16(gb[i], Bs[0] + (i * 256 + w * 64) * 8);
        ga[i] += 64; gb[i] += 64;
    }

    const int niter = K >> 6;
    for (int it = 0; it < niter; it++) {
        const int buf = it & 1;
        __syncthreads();   // drains prefetch into buf (issued prev iter)
        if (it + 1 < niter) {
#pragma unroll
            for (int i = 0; i < 4; i++) {
                gload16(ga[i], As[buf ^ 1] + (i * 256 + w * 64) * 8);
                gload16(gb[i], Bs[buf ^ 1] + (i * 256 + w * 64) * 8);
                ga[i] += 64; gb[i] += 64;
            }
        }

#pragma unroll
        for (int s = 0; s < 2; s++) {
            bf16x8 af[4], bfr[4];
#pragma unroll
            for (int t = 0; t < 4; t++) {
                af[t]  = *(const bf16x8*)((const char*)As[buf] + offA[s][t]);
                bfr[t] = *(const bf16x8*)((const char*)Bs[buf] + offB[s][t]);
            }
#pragma unroll
            for (int mt = 0; mt < 4; mt++)
#pragma unroll
                for (int nt = 0; nt < 4; nt++)
                    acc[mt][nt] = MFMA16(af[mt], bfr[nt], acc[mt][nt]);
        }
    }

#pragma unroll
    for (int mt = 0; mt < 4; mt++)
#pragma unroll
        for (int nt = 0; nt < 4; nt++) {
            const int row = m0 + wm * 64 + mt * 16 + quad * 4;
            const int col = n0 + wn * 64 + nt * 16 + l16;
            const float bv = BIAS ? bias[col] : 0.0f;
#pragma unroll
            for (int r = 0; r < 4; r++) {
                float v = acc[mt][nt][r] + bv;
                if (RELU) v = v > 0.0f ? v : 0.0f;
                const size_t idx = (size_t)(row + r) * N + col;
                if (RESID) v += resid[idx];
                if (OUTBF) ((__hip_bfloat16*)out)[idx] = __float2bfloat16(v);
                else       ((float*)out)[idx] = v;
            }
        }
}

// ------------------- GEMM, BM=64 BN=64 BK=64, dbuf 1-barrier -----------------
// For N=1024 outputs: grid (N/64)x(M/64) = 1024 blocks -> 4 blocks/CU.
template <int BIAS, int RELU, int RESID, int OUTBF>
__global__ __launch_bounds__(256, 4) void gemm6464_k(const __hip_bfloat16* __restrict__ A,
                                                     const __hip_bfloat16* __restrict__ Bt,
                                                     const float* __restrict__ bias,
                                                     const float* __restrict__ resid,
                                                     void* __restrict__ out,
                                                     int M, int N, int K) {
    __align__(16) __shared__ __hip_bfloat16 As[2][64 * 64];
    __align__(16) __shared__ __hip_bfloat16 Bs[2][64 * 64];

    const int tid  = threadIdx.x;
    const int lane = tid & 63, w = tid >> 6;
    const int wm = w >> 1, wn = w & 1;             // 2x2 wave grid of 32x32
    const int nbx = gridDim.x;
    const int flat = xcd_swizzle(blockIdx.y * nbx + blockIdx.x, nbx * gridDim.y);
    const int m0 = (flat / nbx) * 64, n0 = (flat % nbx) * 64;
    const int l16 = lane & 15, quad = lane >> 4;

    const int srw = lane >> 3;
    const int scn = ((lane & 7) - srw) & 7;

    const __hip_bfloat16* ga[2];
    const __hip_bfloat16* gb[2];
#pragma unroll
    for (int i = 0; i < 2; i++) {
        const int row = i * 32 + w * 8 + srw;
        ga[i] = A  + (size_t)(m0 + row) * K + scn * 8;
        gb[i] = Bt + (size_t)(n0 + row) * K + scn * 8;
    }

    int offA[2][2], offB[2][2];
#pragma unroll
    for (int s = 0; s < 2; s++)
#pragma unroll
        for (int t = 0; t < 2; t++) {
            const int rA = wm * 32 + t * 16 + l16;
            offA[s][t] = (rA * 8 + ((s * 4 + quad + (rA & 7)) & 7)) * 16;
            const int rB = wn * 32 + t * 16 + l16;
            offB[s][t] = (rB * 8 + ((s * 4 + quad + (rB & 7)) & 7)) * 16;
        }

    f32x4 acc[2][2] = {};

#pragma unroll
    for (int i = 0; i < 2; i++) {
        gload16(ga[i], As[0] + (i * 256 + w * 64) * 8);
        gload16(gb[i], Bs[0] + (i * 256 + w * 64) * 8);
        ga[i] += 64; gb[i] += 64;
    }

    const int niter = K >> 6;
    for (int it = 0; it < niter; it++) {
        const int buf = it & 1;
        __syncthreads();   // drains prefetch into buf
        if (it + 1 < niter) {
#pragma unroll
            for (int i = 0; i < 2; i++) {
                gload16(ga[i], As[buf ^ 1] + (i * 256 + w * 64) * 8);
                gload16(gb[i], Bs[buf ^ 1] + (i * 256 + w * 64) * 8);
                ga[i] += 64; gb[i] += 64;
            }
        }

#pragma unroll
        for (int s = 0; s < 2; s++) {
            bf16x8 af[2], bfr[2];
#pragma unroll
            for (int t = 0; t < 2; t++) {
                af[t]  = *(const bf16x8*)((const char*)As[buf] + offA[s][t]);
                bfr[t] = *(const bf16x8*)((const char*)Bs[buf] + offB[s][t]);
            }
#pragma unroll
            for (int mt = 0; mt < 2; mt++)
#pragma unroll
                for (int nt = 0; nt < 2; nt++)
                    acc[mt][nt] = MFMA16(af[mt], bfr[nt], acc[mt][nt]);
        }
    }

#pragma unroll
    for (int mt = 0; mt < 2; mt++)
#pragma unroll
        for (int nt = 0; nt < 2; nt++) {
            const int row = m0 + wm * 32 + mt * 16 + quad * 4;
            const int col = n0 + wn * 32 + nt * 16 + l16;
            const float bv = BIAS ? bias[col] : 0.0f;
#pragma unroll
            for (int r = 0; r < 4; r++) {
                float v = acc[mt][nt][r] + bv;
                if (RELU) v = v > 0.0f ? v : 0.0f;
                const size_t idx = (size_t)(row + r) * N + col;
                if (RESID) v += resid[idx];
                if (OUTBF) ((__hip_bfloat16*)out)[idx] = __float2bfloat16(v);
                else       ((float*)out)[idx] = v;
            }
        }
}

// ----------------------- V transpose: qkv -> Vt[bh][d][T] -------------------
__global__ __launch_bounds__(256) void vtrans_k(const __hip_bfloat16* __restrict__ qkv,
                                                __hip_bfloat16* __restrict__ vt) {
    const int T = 2048, C3 = 3072;
    const int bh = blockIdx.y, b = bh >> 4, h = bh & 15;
    const int t0 = blockIdx.x * 64;
    const int tx = threadIdx.x, ty = threadIdx.y;   // block (64, 4)
    __shared__ __hip_bfloat16 tile[64][65];
#pragma unroll
    for (int j = 0; j < 16; j++) {
        const int tl = ty * 16 + j;
        tile[tl][tx] = qkv[(size_t)(b * T + t0 + tl) * C3 + 2048 + h * 64 + tx];
    }
    __syncthreads();
#pragma unroll
    for (int j = 0; j < 16; j++) {
        const int d = ty * 16 + j;
        vt[((size_t)bh * 64 + d) * 2048 + t0 + tx] = tile[tx][d];
    }
}

// ------------------------------ flash attention -----------------------------
__global__ __launch_bounds__(256, 3) void attn_k(const __hip_bfloat16* __restrict__ qkv,
                                                 const __hip_bfloat16* __restrict__ vt,
                                                 __hip_bfloat16* __restrict__ outp) {
    const int T = 2048, C3 = 3072;
    const int bh = blockIdx.x, b = bh >> 4, h = bh & 15;
    const int qt = 31 - blockIdx.y;           // heavy q-tiles dispatched first
    const int q0 = qt * 64;
    const int tid = threadIdx.x, lane = tid & 63, w = tid >> 6;
    const int l16 = lane & 15, quad = lane >> 4;

    __align__(16) __shared__ __hip_bfloat16 Ks[2][64 * 64];   // swizzled [key][d]
    __align__(16) __shared__ __hip_bfloat16 Vs[2][64 * 64];   // swizzled [d][key]
    __align__(16) __shared__ __hip_bfloat16 Pw[4][16 * 72];   // per-wave P

    const float sc = 0.125f * 1.44269504f;
    bf16x8 qf0, qf1;
    {
        const __hip_bfloat16* qp =
            qkv + (size_t)(b * T + q0 + w * 16 + l16) * C3 + h * 64;
        bf16x8 a = *(const bf16x8*)(qp + quad * 8);
        bf16x8 c = *(const bf16x8*)(qp + 32 + quad * 8);
#pragma unroll
        for (int i = 0; i < 8; i++) {
            union { unsigned int u; float f; } ua, uc;
            ua.u = ((unsigned int)(unsigned short)a[i]) << 16;
            uc.u = ((unsigned int)(unsigned short)c[i]) << 16;
            qf0[i] = (short)(__bfloat16_as_ushort(__float2bfloat16(ua.f * sc)));
            qf1[i] = (short)(__bfloat16_as_ushort(__float2bfloat16(uc.f * sc)));
        }
    }

    const int srw = lane >> 3;
    const int scn = ((lane & 7) - srw) & 7;
    const __hip_bfloat16* kp[2];
    const __hip_bfloat16* vp[2];
#pragma unroll
    for (int i = 0; i < 2; i++) {
        const int row = i * 32 + w * 8 + srw;
        kp[i] = qkv + (size_t)(b * T + row) * C3 + 1024 + h * 64 + scn * 8;
        vp[i] = vt + ((size_t)bh * 64 + row) * 2048 + scn * 8;
    }

    int offK[2][4];
#pragma unroll
    for (int s = 0; s < 2; s++)
#pragma unroll
        for (int t = 0; t < 4; t++) {
            const int rr = t * 16 + l16;
            offK[s][t] = (rr * 8 + ((s * 4 + quad + (rr & 7)) & 7)) * 16;
        }

    f32x4 oacc[4] = {};
    float lpart[4] = {0.0f, 0.0f, 0.0f, 0.0f};

#pragma unroll
    for (int i = 0; i < 2; i++) {
        gload16(kp[i], Ks[0] + (i * 256 + w * 64) * 8);
        gload16(vp[i], Vs[0] + (i * 256 + w * 64) * 8);
    }

    for (int kt = 0; kt <= qt; kt++) {
        const int buf = kt & 1;
        __syncthreads();
        if (kt < qt) {
#pragma unroll
            for (int i = 0; i < 2; i++) {
                gload16(kp[i] + (size_t)(kt + 1) * 64 * C3,
                        Ks[buf ^ 1] + (i * 256 + w * 64) * 8);
                gload16(vp[i] + (kt + 1) * 64,
                        Vs[buf ^ 1] + (i * 256 + w * 64) * 8);
            }
        }

        f32x4 s4[4];
#pragma unroll
        for (int nt = 0; nt < 4; nt++) {
            bf16x8 kf0 = *(const bf16x8*)((const char*)Ks[buf] + offK[0][nt]);
            bf16x8 kf1 = *(const bf16x8*)((const char*)Ks[buf] + offK[1][nt]);
            f32x4 z = {};
            z = MFMA16(qf0, kf0, z);
            z = MFMA16(qf1, kf1, z);
            s4[nt] = z;
        }

        const bool diag = (kt == qt);
        const int myrow = w * 16 + quad * 4;
#pragma unroll
        for (int nt = 0; nt < 4; nt++) {
            const int col = nt * 16 + l16;
#pragma unroll
            for (int r = 0; r < 4; r++) {
                float p = exp2f(s4[nt][r]);
                if (diag && col > myrow + r) p = 0.0f;
                lpart[r] += p;
                Pw[w][(quad * 4 + r) * 72 + col] = __float2bfloat16(p);
            }
        }

        asm volatile("s_waitcnt lgkmcnt(0)" ::: "memory");

        bf16x8 pf0 = *(const bf16x8*)(&Pw[w][l16 * 72 + quad * 8]);
        bf16x8 pf1 = *(const bf16x8*)(&Pw[w][l16 * 72 + 32 + quad * 8]);
#pragma unroll
        for (int dt = 0; dt < 4; dt++) {
            bf16x8 vf0 = *(const bf16x8*)((const char*)Vs[buf] + offK[0][dt]);
            bf16x8 vf1 = *(const bf16x8*)((const char*)Vs[buf] + offK[1][dt]);
            oacc[dt] = MFMA16(pf0, vf0, oacc[dt]);
            oacc[dt] = MFMA16(pf1, vf1, oacc[dt]);
        }
    }

#pragma unroll
    for (int off = 1; off < 16; off <<= 1)
#pragma unroll
        for (int r = 0; r < 4; r++)
            lpart[r] += __shfl_xor(lpart[r], off, 64);

    float rl[4];
#pragma unroll
    for (int r = 0; r < 4; r++) rl[r] = 1.0f / lpart[r];
#pragma unroll
    for (int dt = 0; dt < 4; dt++)
#pragma unroll
        for (int r = 0; r < 4; r++) {
            const int row = q0 + w * 16 + quad * 4 + r;
            outp[(size_t)(b * T + row) * 1024 + h * 64 + dt * 16 + l16] =
                __float2bfloat16(oacc[dt][r] * rl[r]);
        }
}

// --------------------------------- launcher --------------------------------
extern "C" void kernel_launch(void* const* d_in, const int* in_sizes, int n_in,
                              void* d_out, int out_size, void* d_ws, size_t ws_size,
                              hipStream_t stream) {
    const float* x     = (const float*)d_in[0];
    const float* Wqkv  = (const float*)d_in[1];
    const float* Wo    = (const float*)d_in[2];
    const float* b_o   = (const float*)d_in[3];
    const float* g1    = (const float*)d_in[4];
    const float* beta1 = (const float*)d_in[5];
    const float* g2    = (const float*)d_in[6];
    const float* beta2 = (const float*)d_in[7];
    const float* Wff1  = (const float*)d_in[8];
    const float* bff1  = (const float*)d_in[9];
    const float* Wff2  = (const float*)d_in[10];
    const float* bff2  = (const float*)d_in[11];

    char* ws = (char*)d_ws;
    size_t off = 0;
    auto alloc = [&](size_t bytes) {
        void* p = ws + off;
        off += (bytes + 255) & ~(size_t)255;
        return p;
    };
    __hip_bfloat16* Wqkv_t = (__hip_bfloat16*)alloc(3072ULL * 1024 * 2);
    __hip_bfloat16* Wo_t   = (__hip_bfloat16*)alloc(1024ULL * 1024 * 2);
    __hip_bfloat16* Wff1_t = (__hip_bfloat16*)alloc(4096ULL * 1024 * 2);
    __hip_bfloat16* Wff2_t = (__hip_bfloat16*)alloc(1024ULL * 4096 * 2);
    __hip_bfloat16* h_bf   = (__hip_bfloat16*)alloc(4096ULL * 1024 * 2);
    __hip_bfloat16* qkv_bf = (__hip_bfloat16*)alloc(4096ULL * 3072 * 2);
    __hip_bfloat16* att_bf = (__hip_bfloat16*)alloc(4096ULL * 1024 * 2);
    float*          x2     = (float*)alloc(4096ULL * 1024 * 4);
    __hip_bfloat16* ff1_bf = qkv_bf;              // dead by FF time
    __hip_bfloat16* vt     = (__hip_bfloat16*)x2; // dead before Wo-gemm writes x2

    tconv_all<<<6144, dim3(32, 8), 0, stream>>>(Wqkv, Wqkv_t, Wo, Wo_t,
                                                Wff1, Wff1_t, Wff2, Wff2_t);

    ln_k<<<4096, 256, 0, stream>>>(x, g1, beta1, h_bf);
    gemm_k<0, 0, 0, 1><<<dim3(3072 / 128, 4096 / 128), 256, 0, stream>>>(
        h_bf, Wqkv_t, nullptr, nullptr, qkv_bf, 4096, 3072, 1024);
    vtrans_k<<<dim3(32, 32), dim3(64, 4), 0, stream>>>(qkv_bf, vt);
    attn_k<<<dim3(32, 32), 256, 0, stream>>>(qkv_bf, vt, att_bf);
    gemm6464_k<1, 0, 1, 0><<<dim3(1024 / 64, 4096 / 64), 256, 0, stream>>>(
        att_bf, Wo_t, b_o, x, x2, 4096, 1024, 1024);
    ln_k<<<4096, 256, 0, stream>>>(x2, g2, beta2, h_bf);
    gemm_k<1, 1, 0, 1><<<dim3(4096 / 128, 4096 / 128), 256, 0, stream>>>(
        h_bf, Wff1_t, bff1, nullptr, ff1_bf, 4096, 4096, 1024);
    gemm6464_k<1, 0, 1, 0><<<dim3(1024 / 64, 4096 / 64), 256, 0, stream>>>(
        ff1_bf, Wff2_t, bff2, x2, (float*)d_out, 4096, 1024, 4096);
}

// Round 8
// 307.842 us; speedup vs baseline: 1.4182x; 1.0236x over previous
//
#include <hip/hip_runtime.h>
#include <hip/hip_bf16.h>
#include <stdint.h>

// ---------------------------------------------------------------------------
// TransformerDecoderBlock on MI355X (gfx950).  B=2, T=2048, C=1024, H=16, hd=64.
// R15 (champion, 315.1us): R8 GEMM structure + coalesced tconv.
// R9-R14: counted-vmcnt on 2-phase skeletons = null/regressive (guide
//      m131-m141 re-derived). 8-phase is the prerequisite (T-catalog gate).
// R16: gemm256_k = 8-phase 256^2 port (plain HIP) for qkv + FF1 only.
//      512 thr, 2x4 waves, 128x64/wave, LDS 128KB (2dbuf x 2half x 128x64),
//      per phase: {ds-reads (4 or 8 b128), stage 1 half-tile (2 gload16),
//      barrier, setprio(1), 16 MFMA, setprio(0), [vmcnt(2) if staged],
//      barrier}. Stage slots derived so every LDS overwrite is
//      barrier-separated from the victim's last read; vmcnt ledger proven.
//      Wo/FF2 stay on proven gemm6464_k; attn/ln/tconv frozen at R15.
// ---------------------------------------------------------------------------

typedef __attribute__((ext_vector_type(8))) short bf16x8;   // 8 bf16 in 4 VGPRs
typedef __attribute__((ext_vector_type(4))) float f32x4;

#define MFMA16(a, b, c) __builtin_amdgcn_mfma_f32_16x16x32_bf16((a), (b), (c), 0, 0, 0)

__device__ __forceinline__ void gload16(const void* g, void* l) {
    __builtin_amdgcn_global_load_lds(
        (const __attribute__((address_space(1))) char*)g,
        (__attribute__((address_space(3))) char*)l, 16, 0, 0);
}

// XCD-aware remap: contiguous chunk of work per XCD (XCD = dispatch id % 8).
__device__ __forceinline__ int xcd_swizzle(int flat, int nblk) {
    if ((nblk & 7) == 0) {
        const int per = nblk >> 3;
        flat = (flat & 7) * per + (flat >> 3);
    }
    return flat;
}

// ---------------- merged transpose + fp32->bf16 for all 4 weights -----------
// R15: 32(n) x 64(k) tiles; writes packed 2xbf16 -> 128B segments.
__global__ __launch_bounds__(256) void tconv_all(
    const float* __restrict__ w0, __hip_bfloat16* __restrict__ o0,   // 1024x3072
    const float* __restrict__ w1, __hip_bfloat16* __restrict__ o1,   // 1024x1024
    const float* __restrict__ w2, __hip_bfloat16* __restrict__ o2,   // 1024x4096
    const float* __restrict__ w3, __hip_bfloat16* __restrict__ o3) { // 4096x1024
    __shared__ float tile[64][33];                  // [k][n]
    const int f = blockIdx.x;
    const float* in; __hip_bfloat16* out; int K, N, nx, t;
    if (f < 1536)      { in = w0; out = o0; K = 1024; N = 3072; nx = 96;  t = f; }
    else if (f < 2048) { in = w1; out = o1; K = 1024; N = 1024; nx = 32;  t = f - 1536; }
    else if (f < 4096) { in = w2; out = o2; K = 1024; N = 4096; nx = 128; t = f - 2048; }
    else               { in = w3; out = o3; K = 4096; N = 1024; nx = 32;  t = f - 4096; }
    const int n0 = (t % nx) * 32, k0 = (t / nx) * 64;
    const int tx = threadIdx.x, ty = threadIdx.y;   // block (32, 8)
#pragma unroll
    for (int i = 0; i < 8; i++)
        tile[i * 8 + ty][tx] = in[(size_t)(k0 + i * 8 + ty) * N + n0 + tx];
    __syncthreads();
    for (int i = ty; i < 32; i += 8) {
        const unsigned short lo =
            __bfloat16_as_ushort(__float2bfloat16(tile[2 * tx][i]));
        const unsigned short hi =
            __bfloat16_as_ushort(__float2bfloat16(tile[2 * tx + 1][i]));
        *(uint32_t*)(out + (size_t)(n0 + i) * K + k0 + 2 * tx) =
            ((uint32_t)hi << 16) | lo;
    }
}

// --------------------------------- layernorm -------------------------------
__global__ __launch_bounds__(256) void ln_k(const float* __restrict__ x,
                                            const float* __restrict__ g,
                                            const float* __restrict__ beta,
                                            __hip_bfloat16* __restrict__ out) {
    const int row = blockIdx.x;
    const int tid = threadIdx.x;
    float4 v = ((const float4*)(x + (size_t)row * 1024))[tid];
    float s  = v.x + v.y + v.z + v.w;
    float s2 = v.x * v.x + v.y * v.y + v.z * v.z + v.w * v.w;
    for (int off = 1; off < 64; off <<= 1) {
        s  += __shfl_xor(s,  off, 64);
        s2 += __shfl_xor(s2, off, 64);
    }
    __shared__ float ss[4], ss2[4];
    const int w = tid >> 6, lane = tid & 63;
    if (lane == 0) { ss[w] = s; ss2[w] = s2; }
    __syncthreads();
    s  = ss[0] + ss[1] + ss[2] + ss[3];
    s2 = ss2[0] + ss2[1] + ss2[2] + ss2[3];
    const float mu  = s * (1.0f / 1024.0f);
    const float var = s2 * (1.0f / 1024.0f) - mu * mu;
    const float rs  = rsqrtf(var + 1e-5f);
    float4 gv = ((const float4*)g)[tid];
    float4 bv = ((const float4*)beta)[tid];
    __hip_bfloat16* o = out + (size_t)row * 1024 + tid * 4;
    o[0] = __float2bfloat16((v.x - mu) * rs * gv.x + bv.x);
    o[1] = __float2bfloat16((v.y - mu) * rs * gv.y + bv.y);
    o[2] = __float2bfloat16((v.z - mu) * rs * gv.z + bv.z);
    o[3] = __float2bfloat16((v.w - mu) * rs * gv.w + bv.w);
}

// ----------- 8-phase GEMM, BM=BN=256 BK=64, 512 threads, 2x4 waves ----------
// Per wave: 128x64 output = acc[8][4] f32x4. LDS: [dbuf][half][128*64] per
// operand (128KB). Proven 8-chunk swizzle (R8, 0 conflicts). Per K-tile-pair
// iteration: 8 phases; quadrants (mh,nh) = 00,01,11,10 per tile; one
// half-tile staged per phase; vmcnt(2) at the two staging-boundary phases.
// WAR-safety: A halves of a dbuf are last read at q2, B halves at q3; stage
// slots (see PH calls) always land one-phase-after the victim's last read.
// RAW-safety ledger: vmcnt(2) leaves only the just-issued half outstanding,
// so the next tile's 4 halves are always landed before its q0 reads.
template <int BIAS, int RELU>
__global__ __launch_bounds__(512, 2) void gemm256_k(const __hip_bfloat16* __restrict__ A,
                                                    const __hip_bfloat16* __restrict__ Bt,
                                                    const float* __restrict__ bias,
                                                    __hip_bfloat16* __restrict__ out,
                                                    int M, int N, int K) {
    __align__(16) __shared__ __hip_bfloat16 As[2][2][128 * 64];  // [dbuf][half]
    __align__(16) __shared__ __hip_bfloat16 Bs[2][2][128 * 64];

    const int tid  = threadIdx.x;
    const int lane = tid & 63, w = tid >> 6;        // 8 waves
    const int wm = w >> 2, wn = w & 3;              // 2(M) x 4(N)
    const int nbx = gridDim.x;
    const int flat = xcd_swizzle(blockIdx.y * nbx + blockIdx.x, nbx * gridDim.y);
    const int m0 = (flat / nbx) * 256, n0 = (flat % nbx) * 256;
    const int l16 = lane & 15, quad = lane >> 4;

    const int srw = lane >> 3;                 // 0..7
    const int scn = ((lane & 7) - srw) & 7;    // swizzled source chunk

    // staging source pointers: [half][i]; rows h*128 + i*64 + w*8 + srw
    const __hip_bfloat16* gA[2][2];
    const __hip_bfloat16* gB[2][2];
#pragma unroll
    for (int h = 0; h < 2; h++)
#pragma unroll
        for (int i = 0; i < 2; i++) {
            const int r = h * 128 + i * 64 + w * 8 + srw;
            gA[h][i] = A  + (size_t)(m0 + r) * K + scn * 8;
            gB[h][i] = Bt + (size_t)(n0 + r) * K + scn * 8;
        }

    // read byte offsets (within [dbuf][half], +mh*8192 / +nh*4096 at use)
    int offA[2][4], offB[2][2];
#pragma unroll
    for (int s = 0; s < 2; s++) {
#pragma unroll
        for (int t = 0; t < 4; t++) {
            const int r = t * 16 + l16;
            offA[s][t] = (r * 8 + ((s * 4 + quad + (r & 7)) & 7)) * 16;
        }
#pragma unroll
        for (int t = 0; t < 2; t++) {
            const int r = (wn & 1) * 64 + t * 16 + l16;
            offB[s][t] = (r * 8 + ((s * 4 + quad + (r & 7)) & 7)) * 16;
        }
    }
    const char* AsW = (const char*)&As[0][wm][0];       // +D*32768 +MH*8192
    const char* BsW = (const char*)&Bs[0][wn >> 1][0];  // +D*32768 +NH*4096

    f32x4 acc[8][4] = {};
    bf16x8 a[2][4], b[2][2];

    const int NT = K >> 6;   // K-tiles; K=1024 -> 16 (even, >=2)

#define STG_A(ST, SH, D)                                                      \
    do { if ((ST) < NT) {                                                     \
        _Pragma("unroll") for (int i = 0; i < 2; i++)                         \
            gload16(gA[SH][i] + (size_t)(ST) * 64,                            \
                    &As[D][SH][(i * 64 + w * 8) * 64]);                       \
    } } while (0)
#define STG_B(ST, SH, D)                                                      \
    do { if ((ST) < NT) {                                                     \
        _Pragma("unroll") for (int i = 0; i < 2; i++)                         \
            gload16(gB[SH][i] + (size_t)(ST) * 64,                            \
                    &Bs[D][SH][(i * 64 + w * 8) * 64]);                       \
    } } while (0)
#define VM_NONE do {} while (0)
#define VM_P(X)                                                               \
    do { if ((X) < NT) asm volatile("s_waitcnt vmcnt(2)" ::: "memory");       \
         else          asm volatile("s_waitcnt vmcnt(0)" ::: "memory");       \
    } while (0)

    // PHASE: reads -> stage -> barrier -> MFMA -> [vmcnt] -> barrier
#define PH(RDA, MH, RDB, NH, D, STG, VM)                                      \
    do {                                                                      \
        if (RDA) {                                                            \
            _Pragma("unroll") for (int s = 0; s < 2; s++)                     \
            _Pragma("unroll") for (int t = 0; t < 4; t++)                     \
                a[s][t] = *(const bf16x8*)(AsW + (D) * 32768 + (MH) * 8192 +  \
                                           offA[s][t]);                       \
        }                                                                     \
        if (RDB) {                                                            \
            _Pragma("unroll") for (int s = 0; s < 2; s++)                     \
            _Pragma("unroll") for (int t = 0; t < 2; t++)                     \
                b[s][t] = *(const bf16x8*)(BsW + (D) * 32768 + (NH) * 4096 +  \
                                           offB[s][t]);                       \
        }                                                                     \
        STG;                                                                  \
        __builtin_amdgcn_s_barrier();                                         \
        asm volatile("" ::: "memory");                                        \
        __builtin_amdgcn_s_setprio(1);                                        \
        _Pragma("unroll") for (int s = 0; s < 2; s++)                         \
        _Pragma("unroll") for (int ti = 0; ti < 4; ti++)                      \
        _Pragma("unroll") for (int tj = 0; tj < 2; tj++)                      \
            acc[(MH) * 4 + ti][(NH) * 2 + tj] =                               \
                MFMA16(a[s][ti], b[s][tj], acc[(MH) * 4 + ti][(NH) * 2 + tj]);\
        __builtin_amdgcn_s_setprio(0);                                        \
        VM;                                                                   \
        __builtin_amdgcn_s_barrier();                                         \
        asm volatile("" ::: "memory");                                        \
    } while (0)

    // prologue: tile0 all 4 halves + tile1 A0; wait tile0 landed.
    STG_A(0, 0, 0); STG_A(0, 1, 0); STG_B(0, 0, 0); STG_B(0, 1, 0);
    STG_A(1, 0, 1);
    asm volatile("s_waitcnt vmcnt(2)" ::: "memory");
    __builtin_amdgcn_s_barrier();
    asm volatile("" ::: "memory");

    for (int T = 0; T < NT; T += 2) {
        // tile T from dbuf0, tile T+1 from dbuf1
        PH(1, 0, 1, 0, 0, STG_A(T + 1, 1, 1), VM_NONE);   // p0: q(0,0)
        PH(0, 0, 1, 1, 0, STG_B(T + 1, 0, 1), VM_NONE);   // p1: q(0,1)
        PH(1, 1, 0, 1, 0, STG_B(T + 1, 1, 1), VM_NONE);   // p2: q(1,1)
        PH(0, 1, 1, 0, 0, STG_A(T + 2, 0, 0), VM_P(T + 2)); // p3: q(1,0)
        PH(1, 0, 1, 0, 1, STG_A(T + 2, 1, 0), VM_NONE);   // p4: q(0,0)
        PH(0, 0, 1, 1, 1, STG_B(T + 2, 0, 0), VM_NONE);   // p5: q(0,1)
        PH(1, 1, 0, 1, 1, STG_B(T + 2, 1, 0), VM_NONE);   // p6: q(1,1)
        PH(0, 1, 1, 0, 1, STG_A(T + 3, 0, 1), VM_P(T + 3)); // p7: q(1,0)
    }
#undef PH
#undef VM_P
#undef VM_NONE
#undef STG_B
#undef STG_A

#pragma unroll
    for (int mt = 0; mt < 8; mt++)
#pragma unroll
        for (int nt = 0; nt < 4; nt++) {
            const int row = m0 + wm * 128 + mt * 16 + quad * 4;
            const int col = n0 + wn * 64 + nt * 16 + l16;
            const float bv = BIAS ? bias[col] : 0.0f;
#pragma unroll
            for (int r = 0; r < 4; r++) {
                float v = acc[mt][nt][r] + bv;
                if (RELU) v = v > 0.0f ? v : 0.0f;
                out[(size_t)(row + r) * N + col] = __float2bfloat16(v);
            }
        }
}

// ------------------- GEMM, BM=64 BN=64 BK=64, dbuf 1-barrier -----------------
// For N=1024 outputs: grid (N/64)x(M/64) = 1024 blocks -> 4 blocks/CU.
template <int BIAS, int RELU, int RESID, int OUTBF>
__global__ __launch_bounds__(256, 4) void gemm6464_k(const __hip_bfloat16* __restrict__ A,
                                                     const __hip_bfloat16* __restrict__ Bt,
                                                     const float* __restrict__ bias,
                                                     const float* __restrict__ resid,
                                                     void* __restrict__ out,
                                                     int M, int N, int K) {
    __align__(16) __shared__ __hip_bfloat16 As[2][64 * 64];
    __align__(16) __shared__ __hip_bfloat16 Bs[2][64 * 64];

    const int tid  = threadIdx.x;
    const int lane = tid & 63, w = tid >> 6;
    const int wm = w >> 1, wn = w & 1;             // 2x2 wave grid of 32x32
    const int nbx = gridDim.x;
    const int flat = xcd_swizzle(blockIdx.y * nbx + blockIdx.x, nbx * gridDim.y);
    const int m0 = (flat / nbx) * 64, n0 = (flat % nbx) * 64;
    const int l16 = lane & 15, quad = lane >> 4;

    const int srw = lane >> 3;
    const int scn = ((lane & 7) - srw) & 7;

    const __hip_bfloat16* ga[2];
    const __hip_bfloat16* gb[2];
#pragma unroll
    for (int i = 0; i < 2; i++) {
        const int row = i * 32 + w * 8 + srw;
        ga[i] = A  + (size_t)(m0 + row) * K + scn * 8;
        gb[i] = Bt + (size_t)(n0 + row) * K + scn * 8;
    }

    int offA[2][2], offB[2][2];
#pragma unroll
    for (int s = 0; s < 2; s++)
#pragma unroll
        for (int t = 0; t < 2; t++) {
            const int rA = wm * 32 + t * 16 + l16;
            offA[s][t] = (rA * 8 + ((s * 4 + quad + (rA & 7)) & 7)) * 16;
            const int rB = wn * 32 + t * 16 + l16;
            offB[s][t] = (rB * 8 + ((s * 4 + quad + (rB & 7)) & 7)) * 16;
        }

    f32x4 acc[2][2] = {};

#pragma unroll
    for (int i = 0; i < 2; i++) {
        gload16(ga[i], As[0] + (i * 256 + w * 64) * 8);
        gload16(gb[i], Bs[0] + (i * 256 + w * 64) * 8);
        ga[i] += 64; gb[i] += 64;
    }

    const int niter = K >> 6;
    for (int it = 0; it < niter; it++) {
        const int buf = it & 1;
        __syncthreads();   // drains prefetch into buf
        if (it + 1 < niter) {
#pragma unroll
            for (int i = 0; i < 2; i++) {
                gload16(ga[i], As[buf ^ 1] + (i * 256 + w * 64) * 8);
                gload16(gb[i], Bs[buf ^ 1] + (i * 256 + w * 64) * 8);
                ga[i] += 64; gb[i] += 64;
            }
        }

#pragma unroll
        for (int s = 0; s < 2; s++) {
            bf16x8 af[2], bfr[2];
#pragma unroll
            for (int t = 0; t < 2; t++) {
                af[t]  = *(const bf16x8*)((const char*)As[buf] + offA[s][t]);
                bfr[t] = *(const bf16x8*)((const char*)Bs[buf] + offB[s][t]);
            }
#pragma unroll
            for (int mt = 0; mt < 2; mt++)
#pragma unroll
                for (int nt = 0; nt < 2; nt++)
                    acc[mt][nt] = MFMA16(af[mt], bfr[nt], acc[mt][nt]);
        }
    }

#pragma unroll
    for (int mt = 0; mt < 2; mt++)
#pragma unroll
        for (int nt = 0; nt < 2; nt++) {
            const int row = m0 + wm * 32 + mt * 16 + quad * 4;
            const int col = n0 + wn * 32 + nt * 16 + l16;
            const float bv = BIAS ? bias[col] : 0.0f;
#pragma unroll
            for (int r = 0; r < 4; r++) {
                float v = acc[mt][nt][r] + bv;
                if (RELU) v = v > 0.0f ? v : 0.0f;
                const size_t idx = (size_t)(row + r) * N + col;
                if (RESID) v += resid[idx];
                if (OUTBF) ((__hip_bfloat16*)out)[idx] = __float2bfloat16(v);
                else       ((float*)out)[idx] = v;
            }
        }
}

// ----------------------- V transpose: qkv -> Vt[bh][d][T] -------------------
__global__ __launch_bounds__(256) void vtrans_k(const __hip_bfloat16* __restrict__ qkv,
                                                __hip_bfloat16* __restrict__ vt) {
    const int T = 2048, C3 = 3072;
    const int bh = blockIdx.y, b = bh >> 4, h = bh & 15;
    const int t0 = blockIdx.x * 64;
    const int tx = threadIdx.x, ty = threadIdx.y;   // block (64, 4)
    __shared__ __hip_bfloat16 tile[64][65];
#pragma unroll
    for (int j = 0; j < 16; j++) {
        const int tl = ty * 16 + j;
        tile[tl][tx] = qkv[(size_t)(b * T + t0 + tl) * C3 + 2048 + h * 64 + tx];
    }
    __syncthreads();
#pragma unroll
    for (int j = 0; j < 16; j++) {
        const int d = ty * 16 + j;
        vt[((size_t)bh * 64 + d) * 2048 + t0 + tx] = tile[tx][d];
    }
}

// ------------------------------ flash attention -----------------------------
__global__ __launch_bounds__(256, 3) void attn_k(const __hip_bfloat16* __restrict__ qkv,
                                                 const __hip_bfloat16* __restrict__ vt,
                                                 __hip_bfloat16* __restrict__ outp) {
    const int T = 2048, C3 = 3072;
    const int bh = blockIdx.x, b = bh >> 4, h = bh & 15;
    const int qt = 31 - blockIdx.y;           // heavy q-tiles dispatched first
    const int q0 = qt * 64;
    const int tid = threadIdx.x, lane = tid & 63, w = tid >> 6;
    const int l16 = lane & 15, quad = lane >> 4;

    __align__(16) __shared__ __hip_bfloat16 Ks[2][64 * 64];   // swizzled [key][d]
    __align__(16) __shared__ __hip_bfloat16 Vs[2][64 * 64];   // swizzled [d][key]
    __align__(16) __shared__ __hip_bfloat16 Pw[4][16 * 72];   // per-wave P

    const float sc = 0.125f * 1.44269504f;
    bf16x8 qf0, qf1;
    {
        const __hip_bfloat16* qp =
            qkv + (size_t)(b * T + q0 + w * 16 + l16) * C3 + h * 64;
        bf16x8 a = *(const bf16x8*)(qp + quad * 8);
        bf16x8 c = *(const bf16x8*)(qp + 32 + quad * 8);
#pragma unroll
        for (int i = 0; i < 8; i++) {
            union { unsigned int u; float f; } ua, uc;
            ua.u = ((unsigned int)(unsigned short)a[i]) << 16;
            uc.u = ((unsigned int)(unsigned short)c[i]) << 16;
            qf0[i] = (short)(__bfloat16_as_ushort(__float2bfloat16(ua.f * sc)));
            qf1[i] = (short)(__bfloat16_as_ushort(__float2bfloat16(uc.f * sc)));
        }
    }

    const int srw = lane >> 3;
    const int scn = ((lane & 7) - srw) & 7;
    const __hip_bfloat16* kp[2];
    const __hip_bfloat16* vp[2];
#pragma unroll
    for (int i = 0; i < 2; i++) {
        const int row = i * 32 + w * 8 + srw;
        kp[i] = qkv + (size_t)(b * T + row) * C3 + 1024 + h * 64 + scn * 8;
        vp[i] = vt + ((size_t)bh * 64 + row) * 2048 + scn * 8;
    }

    int offK[2][4];
#pragma unroll
    for (int s = 0; s < 2; s++)
#pragma unroll
        for (int t = 0; t < 4; t++) {
            const int rr = t * 16 + l16;
            offK[s][t] = (rr * 8 + ((s * 4 + quad + (rr & 7)) & 7)) * 16;
        }

    f32x4 oacc[4] = {};
    float lpart[4] = {0.0f, 0.0f, 0.0f, 0.0f};

#pragma unroll
    for (int i = 0; i < 2; i++) {
        gload16(kp[i], Ks[0] + (i * 256 + w * 64) * 8);
        gload16(vp[i], Vs[0] + (i * 256 + w * 64) * 8);
    }

    for (int kt = 0; kt <= qt; kt++) {
        const int buf = kt & 1;
        __syncthreads();
        if (kt < qt) {
#pragma unroll
            for (int i = 0; i < 2; i++) {
                gload16(kp[i] + (size_t)(kt + 1) * 64 * C3,
                        Ks[buf ^ 1] + (i * 256 + w * 64) * 8);
                gload16(vp[i] + (kt + 1) * 64,
                        Vs[buf ^ 1] + (i * 256 + w * 64) * 8);
            }
        }

        f32x4 s4[4];
#pragma unroll
        for (int nt = 0; nt < 4; nt++) {
            bf16x8 kf0 = *(const bf16x8*)((const char*)Ks[buf] + offK[0][nt]);
            bf16x8 kf1 = *(const bf16x8*)((const char*)Ks[buf] + offK[1][nt]);
            f32x4 z = {};
            z = MFMA16(qf0, kf0, z);
            z = MFMA16(qf1, kf1, z);
            s4[nt] = z;
        }

        const bool diag = (kt == qt);
        const int myrow = w * 16 + quad * 4;
#pragma unroll
        for (int nt = 0; nt < 4; nt++) {
            const int col = nt * 16 + l16;
#pragma unroll
            for (int r = 0; r < 4; r++) {
                float p = exp2f(s4[nt][r]);
                if (diag && col > myrow + r) p = 0.0f;
                lpart[r] += p;
                Pw[w][(quad * 4 + r) * 72 + col] = __float2bfloat16(p);
            }
        }

        asm volatile("s_waitcnt lgkmcnt(0)" ::: "memory");

        bf16x8 pf0 = *(const bf16x8*)(&Pw[w][l16 * 72 + quad * 8]);
        bf16x8 pf1 = *(const bf16x8*)(&Pw[w][l16 * 72 + 32 + quad * 8]);
#pragma unroll
        for (int dt = 0; dt < 4; dt++) {
            bf16x8 vf0 = *(const bf16x8*)((const char*)Vs[buf] + offK[0][dt]);
            bf16x8 vf1 = *(const bf16x8*)((const char*)Vs[buf] + offK[1][dt]);
            oacc[dt] = MFMA16(pf0, vf0, oacc[dt]);
            oacc[dt] = MFMA16(pf1, vf1, oacc[dt]);
        }
    }

#pragma unroll
    for (int off = 1; off < 16; off <<= 1)
#pragma unroll
        for (int r = 0; r < 4; r++)
            lpart[r] += __shfl_xor(lpart[r], off, 64);

    float rl[4];
#pragma unroll
    for (int r = 0; r < 4; r++) rl[r] = 1.0f / lpart[r];
#pragma unroll
    for (int dt = 0; dt < 4; dt++)
#pragma unroll
        for (int r = 0; r < 4; r++) {
            const int row = q0 + w * 16 + quad * 4 + r;
            outp[(size_t)(b * T + row) * 1024 + h * 64 + dt * 16 + l16] =
                __float2bfloat16(oacc[dt][r] * rl[r]);
        }
}

// --------------------------------- launcher --------------------------------
extern "C" void kernel_launch(void* const* d_in, const int* in_sizes, int n_in,
                              void* d_out, int out_size, void* d_ws, size_t ws_size,
                              hipStream_t stream) {
    const float* x     = (const float*)d_in[0];
    const float* Wqkv  = (const float*)d_in[1];
    const float* Wo    = (const float*)d_in[2];
    const float* b_o   = (const float*)d_in[3];
    const float* g1    = (const float*)d_in[4];
    const float* beta1 = (const float*)d_in[5];
    const float* g2    = (const float*)d_in[6];
    const float* beta2 = (const float*)d_in[7];
    const float* Wff1  = (const float*)d_in[8];
    const float* bff1  = (const float*)d_in[9];
    const float* Wff2  = (const float*)d_in[10];
    const float* bff2  = (const float*)d_in[11];

    char* ws = (char*)d_ws;
    size_t off = 0;
    auto alloc = [&](size_t bytes) {
        void* p = ws + off;
        off += (bytes + 255) & ~(size_t)255;
        return p;
    };
    __hip_bfloat16* Wqkv_t = (__hip_bfloat16*)alloc(3072ULL * 1024 * 2);
    __hip_bfloat16* Wo_t   = (__hip_bfloat16*)alloc(1024ULL * 1024 * 2);
    __hip_bfloat16* Wff1_t = (__hip_bfloat16*)alloc(4096ULL * 1024 * 2);
    __hip_bfloat16* Wff2_t = (__hip_bfloat16*)alloc(1024ULL * 4096 * 2);
    __hip_bfloat16* h_bf   = (__hip_bfloat16*)alloc(4096ULL * 1024 * 2);
    __hip_bfloat16* qkv_bf = (__hip_bfloat16*)alloc(4096ULL * 3072 * 2);
    __hip_bfloat16* att_bf = (__hip_bfloat16*)alloc(4096ULL * 1024 * 2);
    float*          x2     = (float*)alloc(4096ULL * 1024 * 4);
    __hip_bfloat16* ff1_bf = qkv_bf;              // dead by FF time
    __hip_bfloat16* vt     = (__hip_bfloat16*)x2; // dead before Wo-gemm writes x2

    tconv_all<<<6144, dim3(32, 8), 0, stream>>>(Wqkv, Wqkv_t, Wo, Wo_t,
                                                Wff1, Wff1_t, Wff2, Wff2_t);

    ln_k<<<4096, 256, 0, stream>>>(x, g1, beta1, h_bf);
    gemm256_k<0, 0><<<dim3(3072 / 256, 4096 / 256), 512, 0, stream>>>(
        h_bf, Wqkv_t, nullptr, qkv_bf, 4096, 3072, 1024);
    vtrans_k<<<dim3(32, 32), dim3(64, 4), 0, stream>>>(qkv_bf, vt);
    attn_k<<<dim3(32, 32), 256, 0, stream>>>(qkv_bf, vt, att_bf);
    gemm6464_k<1, 0, 1, 0><<<dim3(1024 / 64, 4096 / 64), 256, 0, stream>>>(
        att_bf, Wo_t, b_o, x, x2, 4096, 1024, 1024);
    ln_k<<<4096, 256, 0, stream>>>(x2, g2, beta2, h_bf);
    gemm256_k<1, 1><<<dim3(4096 / 256, 4096 / 256), 512, 0, stream>>>(
        h_bf, Wff1_t, bff1, ff1_bf, 4096, 4096, 1024);
    gemm6464_k<1, 0, 1, 0><<<dim3(1024 / 64, 4096 / 64), 256, 0, stream>>>(
        ff1_bf, Wff2_t, bff2, x2, (float*)d_out, 4096, 1024, 4096);
}